// Round 2
// baseline (617.372 us; speedup 1.0000x reference)
//
#include <hip/hip_runtime.h>
#include <hip/hip_bf16.h>

// Problem constants
#define B_      1024
#define CIN     9
#define T0_     2048
#define C1_     16
#define T1_     1024
#define C2_     32
#define RT_     512
#define NNODES  (B_ * RT_)     // 524288
#define HID_    128
#define OUTF_   64

// ---------- helpers ----------
__device__ __forceinline__ float bf2f(unsigned short u) {
    union { unsigned int i; float f; } c; c.i = ((unsigned int)u) << 16; return c.f;
}
__device__ __forceinline__ unsigned short f2bf(float f) {
    union { float f; unsigned int i; } c; c.f = f;
    unsigned int i = c.i + 0x7FFFu + ((c.i >> 16) & 1u);  // round-nearest-even
    return (unsigned short)(i >> 16);
}
__device__ __forceinline__ float4 ld_bf16x4(const unsigned short* p) {
    ushort4 u = *(const ushort4*)p;
    float4 v; v.x = bf2f(u.x); v.y = bf2f(u.y); v.z = bf2f(u.z); v.w = bf2f(u.w);
    return v;
}
__device__ __forceinline__ void st_bf16x4(unsigned short* p, float4 v) {
    ushort4 u; u.x = f2bf(v.x); u.y = f2bf(v.y); u.z = f2bf(v.z); u.w = f2bf(v.w);
    *(ushort4*)p = u;
}
__device__ __forceinline__ float4 relu4(float4 v) {
    v.x = fmaxf(v.x, 0.f); v.y = fmaxf(v.y, 0.f);
    v.z = fmaxf(v.z, 0.f); v.w = fmaxf(v.w, 0.f); return v;
}
__device__ __forceinline__ float4 max4(float4 a, float4 b) {
    float4 v; v.x = fmaxf(a.x, b.x); v.y = fmaxf(a.y, b.y);
    v.z = fmaxf(a.z, b.z); v.w = fmaxf(a.w, b.w); return v;
}
__device__ __forceinline__ float dinv_of(int r) {
    return (r == 0 || r == RT_ - 1) ? 0.70710678118f : 0.57735026919f;
}

// ---------- kernel 1: conv1 (9->16, k=5, pad=2) + ReLU + MaxPool2 ----------
// x: fp32 [B][9][2048] -> y1: bf16 [B][16][1024]
__global__ __launch_bounds__(256) void conv1_pool(
    const float* __restrict__ x, const float* __restrict__ w,
    const float* __restrict__ bias, unsigned short* __restrict__ y1)
{
    __shared__ float xs[CIN][516];
    __shared__ float wT[CIN * 5 * 16];   // [cin][k][co]
    __shared__ float bls[16];
    const int tid = threadIdx.x;
    const int chunk = blockIdx.x;        // 0..3
    const int b = blockIdx.y;

    for (int idx = tid; idx < CIN * 5 * 16; idx += 256) {
        int co = idx / 45, rem = idx % 45;
        int ci = rem / 5, k = rem % 5;
        wT[(ci * 5 + k) * 16 + co] = w[idx];  // w layout [co][ci][k]
    }
    if (tid < 16) bls[tid] = bias[tid];

    const int t0 = chunk * 512;
    const float* xb = x + (size_t)b * CIN * T0_;
    for (int idx = tid; idx < CIN * 516; idx += 256) {
        int ci = idx / 516, j = idx % 516;
        int gt = t0 - 2 + j;
        xs[ci][j] = (gt >= 0 && gt < T0_) ? xb[ci * T0_ + gt] : 0.0f;
    }
    __syncthreads();

    float4 acc0[4] = {}; float4 acc1[4] = {};
    const int base = 2 * tid;
    for (int ci = 0; ci < CIN; ci++) {
        float xw[6];
        #pragma unroll
        for (int j = 0; j < 6; j++) xw[j] = xs[ci][base + j];
        #pragma unroll
        for (int k = 0; k < 5; k++) {
            const float4* wv4 = (const float4*)&wT[(ci * 5 + k) * 16];
            #pragma unroll
            for (int j = 0; j < 4; j++) {
                float4 wv = wv4[j];
                acc0[j].x += wv.x * xw[k];   acc0[j].y += wv.y * xw[k];
                acc0[j].z += wv.z * xw[k];   acc0[j].w += wv.w * xw[k];
                acc1[j].x += wv.x * xw[k+1]; acc1[j].y += wv.y * xw[k+1];
                acc1[j].z += wv.z * xw[k+1]; acc1[j].w += wv.w * xw[k+1];
            }
        }
    }
    const int tp = chunk * 256 + tid;
    unsigned short* yb = y1 + ((size_t)b * C1_) * T1_ + tp;
    #pragma unroll
    for (int j = 0; j < 4; j++) {
        float4 m = max4(acc0[j], acc1[j]);
        const float4 bv = *(const float4*)&bls[4 * j];
        yb[(4*j+0) * T1_] = f2bf(fmaxf(m.x + bv.x, 0.f));
        yb[(4*j+1) * T1_] = f2bf(fmaxf(m.y + bv.y, 0.f));
        yb[(4*j+2) * T1_] = f2bf(fmaxf(m.z + bv.z, 0.f));
        yb[(4*j+3) * T1_] = f2bf(fmaxf(m.w + bv.w, 0.f));
    }
}

// ---------- kernel 2: conv2 (16->32) + ReLU + MaxPool2, writes node-major ----------
// y1: bf16 [B][16][1024] -> y2t: bf16 [B*512][32]
__global__ __launch_bounds__(256) void conv2_pool(
    const unsigned short* __restrict__ y1, const float* __restrict__ w,
    const float* __restrict__ bias, unsigned short* __restrict__ y2t)
{
    __shared__ float xs[C1_][516];
    __shared__ float wT[C1_ * 5 * 32];   // [cin][k][co]
    __shared__ float bls[32];
    const int tid = threadIdx.x;
    const int chunk = blockIdx.x;        // 0..1
    const int b = blockIdx.y;

    for (int idx = tid; idx < C1_ * 5 * 32; idx += 256) {
        int co = idx / 80, rem = idx % 80;
        int ci = rem / 5, k = rem % 5;
        wT[(ci * 5 + k) * 32 + co] = w[idx];  // w layout [co][ci][k]
    }
    if (tid < 32) bls[tid] = bias[tid];

    const int t0 = chunk * 512;
    const unsigned short* xb = y1 + (size_t)b * C1_ * T1_;
    for (int idx = tid; idx < C1_ * 516; idx += 256) {
        int ci = idx / 516, j = idx % 516;
        int gt = t0 - 2 + j;
        xs[ci][j] = (gt >= 0 && gt < T1_) ? bf2f(xb[ci * T1_ + gt]) : 0.0f;
    }
    __syncthreads();

    float4 acc0[8] = {}; float4 acc1[8] = {};
    const int base = 2 * tid;
    for (int ci = 0; ci < C1_; ci++) {
        float xw[6];
        #pragma unroll
        for (int j = 0; j < 6; j++) xw[j] = xs[ci][base + j];
        #pragma unroll
        for (int k = 0; k < 5; k++) {
            const float4* wv4 = (const float4*)&wT[(ci * 5 + k) * 32];
            #pragma unroll
            for (int j = 0; j < 8; j++) {
                float4 wv = wv4[j];
                acc0[j].x += wv.x * xw[k];   acc0[j].y += wv.y * xw[k];
                acc0[j].z += wv.z * xw[k];   acc0[j].w += wv.w * xw[k];
                acc1[j].x += wv.x * xw[k+1]; acc1[j].y += wv.y * xw[k+1];
                acc1[j].z += wv.z * xw[k+1]; acc1[j].w += wv.w * xw[k+1];
            }
        }
    }
    const int tp = chunk * 256 + tid;               // 0..511
    const size_t n = (size_t)b * RT_ + tp;
    unsigned short* row = y2t + n * 32;
    #pragma unroll
    for (int j = 0; j < 8; j++) {
        float4 m = max4(acc0[j], acc1[j]);
        const float4 bv = *(const float4*)&bls[4 * j];
        m.x = fmaxf(m.x + bv.x, 0.f); m.y = fmaxf(m.y + bv.y, 0.f);
        m.z = fmaxf(m.z + bv.z, 0.f); m.w = fmaxf(m.w + bv.w, 0.f);
        st_bf16x4(row + 4 * j, m);
    }
}

// ---------- kernel 3: GCN1 = relu(stencil(y2t) @ W1 + b1) -> h1 [N][128] bf16 ----------
__global__ __launch_bounds__(256) void gcn1_kernel(
    const unsigned short* __restrict__ X,   // [N][32] bf16
    const float* __restrict__ W,            // [32][128] fp32
    const float* __restrict__ bias,         // [128]
    unsigned short* __restrict__ H1)        // [N][128] bf16
{
    __shared__ float As[128 * 36];   // stride 36: 16B-aligned float4 slots, padded
    __shared__ float Ws[32 * 128];
    __shared__ float bls[128];
    const int tid = threadIdx.x;
    const int n0 = blockIdx.x * 128;
    const int r0 = n0 & (RT_ - 1);

    for (int idx = tid; idx < 32 * 128; idx += 256) Ws[idx] = W[idx];
    if (tid < 128) bls[tid] = bias[tid];

    for (int s = tid; s < 1024; s += 256) {
        int i = s >> 3, k4 = (s & 7) * 4;
        int r = r0 + i, n = n0 + i;
        float dm = dinv_of(r);
        float cm = dm * dm;
        float4 v = ld_bf16x4(&X[(size_t)n * 32 + k4]);
        v.x *= cm; v.y *= cm; v.z *= cm; v.w *= cm;
        if (r > 0) {
            float cl = dm * dinv_of(r - 1);
            float4 xl = ld_bf16x4(&X[(size_t)(n - 1) * 32 + k4]);
            v.x += cl * xl.x; v.y += cl * xl.y; v.z += cl * xl.z; v.w += cl * xl.w;
        }
        if (r < RT_ - 1) {
            float cr = dm * dinv_of(r + 1);
            float4 xr = ld_bf16x4(&X[(size_t)(n + 1) * 32 + k4]);
            v.x += cr * xr.x; v.y += cr * xr.y; v.z += cr * xr.z; v.w += cr * xr.w;
        }
        *(float4*)&As[i * 36 + k4] = v;
    }
    __syncthreads();

    const int tx = tid & 15, ty = tid >> 4;
    const int c0 = tx * 4, c1 = 64 + tx * 4;
    const int rb0 = ty * 4, rb1 = 64 + ty * 4;
    float4 acc[8][2] = {};
    #pragma unroll 4
    for (int k = 0; k < 32; k++) {
        float a[8];
        #pragma unroll
        for (int q = 0; q < 4; q++) {
            a[q]     = As[(rb0 + q) * 36 + k];
            a[4 + q] = As[(rb1 + q) * 36 + k];
        }
        float4 b0 = *(const float4*)&Ws[k * 128 + c0];
        float4 b1 = *(const float4*)&Ws[k * 128 + c1];
        #pragma unroll
        for (int rr = 0; rr < 8; rr++) {
            acc[rr][0].x += a[rr] * b0.x; acc[rr][0].y += a[rr] * b0.y;
            acc[rr][0].z += a[rr] * b0.z; acc[rr][0].w += a[rr] * b0.w;
            acc[rr][1].x += a[rr] * b1.x; acc[rr][1].y += a[rr] * b1.y;
            acc[rr][1].z += a[rr] * b1.z; acc[rr][1].w += a[rr] * b1.w;
        }
    }
    const float4 bv0 = *(const float4*)&bls[c0];
    const float4 bv1 = *(const float4*)&bls[c1];
    #pragma unroll
    for (int rr = 0; rr < 8; rr++) {
        int row = (rr < 4) ? (rb0 + rr) : (rb1 + rr - 4);
        float4 v0 = acc[rr][0]; v0.x += bv0.x; v0.y += bv0.y; v0.z += bv0.z; v0.w += bv0.w;
        float4 v1 = acc[rr][1]; v1.x += bv1.x; v1.y += bv1.y; v1.z += bv1.z; v1.w += bv1.w;
        v0 = relu4(v0); v1 = relu4(v1);
        unsigned short* out = H1 + (size_t)(n0 + row) * 128;
        st_bf16x4(out + c0, v0);
        st_bf16x4(out + c1, v1);
    }
}

// ---------- kernel 4: GCN2 tile + ReLU + per-tile column sums (no h2 materialization) ----------
// partials: fp32 [B][4][128]
__global__ __launch_bounds__(256) void gcn2_kernel(
    const unsigned short* __restrict__ H1,  // [N][128] bf16
    const float* __restrict__ W,            // [128][128] fp32
    const float* __restrict__ bias,         // [128]
    float* __restrict__ partials)
{
    __shared__ float As[128 * 36];
    __shared__ float Ws[32 * 128];
    __shared__ float bls[128];
    const int tid = threadIdx.x;
    const int n0 = blockIdx.x * 128;
    const int r0 = n0 & (RT_ - 1);
    if (tid < 128) bls[tid] = bias[tid];

    const int tx = tid & 15, ty = tid >> 4;
    const int c0 = tx * 4, c1 = 64 + tx * 4;
    const int rb0 = ty * 4, rb1 = 64 + ty * 4;
    float4 acc[8][2] = {};

    for (int kc = 0; kc < 4; kc++) {
        for (int idx = tid; idx < 32 * 128; idx += 256)
            Ws[idx] = W[kc * 32 * 128 + idx];
        for (int s = tid; s < 1024; s += 256) {
            int i = s >> 3, k4 = (s & 7) * 4;
            int r = r0 + i, n = n0 + i;
            float dm = dinv_of(r);
            float cm = dm * dm;
            const unsigned short* Xrow = &H1[(size_t)n * 128 + kc * 32 + k4];
            float4 v = ld_bf16x4(Xrow);
            v.x *= cm; v.y *= cm; v.z *= cm; v.w *= cm;
            if (r > 0) {
                float cl = dm * dinv_of(r - 1);
                float4 xl = ld_bf16x4(Xrow - 128);
                v.x += cl * xl.x; v.y += cl * xl.y; v.z += cl * xl.z; v.w += cl * xl.w;
            }
            if (r < RT_ - 1) {
                float cr = dm * dinv_of(r + 1);
                float4 xr = ld_bf16x4(Xrow + 128);
                v.x += cr * xr.x; v.y += cr * xr.y; v.z += cr * xr.z; v.w += cr * xr.w;
            }
            *(float4*)&As[i * 36 + k4] = v;
        }
        __syncthreads();
        #pragma unroll 4
        for (int k = 0; k < 32; k++) {
            float a[8];
            #pragma unroll
            for (int q = 0; q < 4; q++) {
                a[q]     = As[(rb0 + q) * 36 + k];
                a[4 + q] = As[(rb1 + q) * 36 + k];
            }
            float4 b0 = *(const float4*)&Ws[k * 128 + c0];
            float4 b1 = *(const float4*)&Ws[k * 128 + c1];
            #pragma unroll
            for (int rr = 0; rr < 8; rr++) {
                acc[rr][0].x += a[rr] * b0.x; acc[rr][0].y += a[rr] * b0.y;
                acc[rr][0].z += a[rr] * b0.z; acc[rr][0].w += a[rr] * b0.w;
                acc[rr][1].x += a[rr] * b1.x; acc[rr][1].y += a[rr] * b1.y;
                acc[rr][1].z += a[rr] * b1.z; acc[rr][1].w += a[rr] * b1.w;
            }
        }
        __syncthreads();
    }

    // epilogue: relu(acc + bias), column partial sums over this thread's 8 rows
    const float4 bv0 = *(const float4*)&bls[c0];
    const float4 bv1 = *(const float4*)&bls[c1];
    float4 cs0 = {}; float4 cs1 = {};
    #pragma unroll
    for (int rr = 0; rr < 8; rr++) {
        float4 v0 = acc[rr][0]; v0.x += bv0.x; v0.y += bv0.y; v0.z += bv0.z; v0.w += bv0.w;
        float4 v1 = acc[rr][1]; v1.x += bv1.x; v1.y += bv1.y; v1.z += bv1.z; v1.w += bv1.w;
        v0 = relu4(v0); v1 = relu4(v1);
        cs0.x += v0.x; cs0.y += v0.y; cs0.z += v0.z; cs0.w += v0.w;
        cs1.x += v1.x; cs1.y += v1.y; cs1.z += v1.z; cs1.w += v1.w;
    }
    float* red = As;  // reuse As as [16][128] reduction buffer (guarded by last sync)
    *(float4*)&red[ty * 128 + c0] = cs0;
    *(float4*)&red[ty * 128 + c1] = cs1;
    __syncthreads();
    if (tid < 128) {
        float s = 0.f;
        #pragma unroll
        for (int t = 0; t < 16; t++) s += red[t * 128 + tid];
        int batch = n0 >> 9, tile = (n0 >> 7) & 3;
        partials[((batch << 2) + tile) * 128 + tid] = s;
    }
}

// ---------- kernel 5: mean over RT + FC ----------
__global__ __launch_bounds__(128) void fc_kernel(
    const float* __restrict__ partials, const float* __restrict__ fw,
    const float* __restrict__ fb, float* __restrict__ out)
{
    __shared__ float sm[128];
    const int b = blockIdx.x, tid = threadIdx.x;
    float s = 0.f;
    #pragma unroll
    for (int t = 0; t < 4; t++) s += partials[((b << 2) + t) * 128 + tid];
    sm[tid] = s * (1.0f / 512.0f);
    __syncthreads();
    if (tid < 64) {
        float acc = fb[tid];
        #pragma unroll 8
        for (int f = 0; f < 128; f++) acc += sm[f] * fw[f * 64 + tid];
        out[b * 64 + tid] = acc;
    }
}

extern "C" void kernel_launch(void* const* d_in, const int* in_sizes, int n_in,
                              void* d_out, int out_size, void* d_ws, size_t ws_size,
                              hipStream_t stream)
{
    const float* x   = (const float*)d_in[0];
    const float* w1  = (const float*)d_in[1];
    const float* b1  = (const float*)d_in[2];
    const float* w2  = (const float*)d_in[3];
    const float* b2  = (const float*)d_in[4];
    const float* g1w = (const float*)d_in[5];
    const float* g1b = (const float*)d_in[6];
    const float* g2w = (const float*)d_in[7];
    const float* g2b = (const float*)d_in[8];
    const float* fw  = (const float*)d_in[9];
    const float* fb  = (const float*)d_in[10];

    char* ws = (char*)d_ws;
    // bf16 intermediates: y1 32MB @0, y2t 32MB @32MB, h1 128MB @64MB, partials 2MB @192MB
    unsigned short* y1  = (unsigned short*)(ws);
    unsigned short* y2t = (unsigned short*)(ws + (size_t)32 * 1024 * 1024);
    unsigned short* h1  = (unsigned short*)(ws + (size_t)64 * 1024 * 1024);
    float* partials     = (float*)(ws + (size_t)192 * 1024 * 1024);
    float* out = (float*)d_out;

    conv1_pool<<<dim3(4, B_), 256, 0, stream>>>(x, w1, b1, y1);
    conv2_pool<<<dim3(2, B_), 256, 0, stream>>>(y1, w2, b2, y2t);
    gcn1_kernel<<<NNODES / 128, 256, 0, stream>>>(y2t, g1w, g1b, h1);
    gcn2_kernel<<<NNODES / 128, 256, 0, stream>>>(h1, g2w, g2b, partials);
    fc_kernel<<<B_, 128, 0, stream>>>(partials, fw, fb, out);
}

// Round 3
// 459.757 us; speedup vs baseline: 1.3428x; 1.3428x over previous
//
#include <hip/hip_runtime.h>
#include <hip/hip_bf16.h>

// Problem constants
#define B_      1024
#define CIN     9
#define T0_     2048
#define C1_     16
#define T1_     1024
#define C2_     32
#define RT_     512
#define NNODES  (B_ * RT_)     // 524288
#define HID_    128
#define OUTF_   64

typedef __attribute__((ext_vector_type(8))) __bf16 bf16x8;
typedef __attribute__((ext_vector_type(4))) float f32x4;
typedef __attribute__((ext_vector_type(8))) unsigned short us8;

// ---------- helpers ----------
__device__ __forceinline__ float bf2f(unsigned short u) {
    union { unsigned int i; float f; } c; c.i = ((unsigned int)u) << 16; return c.f;
}
__device__ __forceinline__ unsigned short f2bf(float f) {
    union { float f; unsigned int i; } c; c.f = f;
    unsigned int i = c.i + 0x7FFFu + ((c.i >> 16) & 1u);  // round-nearest-even
    return (unsigned short)(i >> 16);
}
__device__ __forceinline__ float4 ld_bf16x4(const unsigned short* p) {
    ushort4 u = *(const ushort4*)p;
    float4 v; v.x = bf2f(u.x); v.y = bf2f(u.y); v.z = bf2f(u.z); v.w = bf2f(u.w);
    return v;
}
__device__ __forceinline__ void st_bf16x4(unsigned short* p, float4 v) {
    ushort4 u; u.x = f2bf(v.x); u.y = f2bf(v.y); u.z = f2bf(v.z); u.w = f2bf(v.w);
    *(ushort4*)p = u;
}
__device__ __forceinline__ float4 max4(float4 a, float4 b) {
    float4 v; v.x = fmaxf(a.x, b.x); v.y = fmaxf(a.y, b.y);
    v.z = fmaxf(a.z, b.z); v.w = fmaxf(a.w, b.w); return v;
}
__device__ __forceinline__ float dinv_of(int r) {
    return (r == 0 || r == RT_ - 1) ? 0.70710678118f : 0.57735026919f;
}

// ---------- kernel 1: conv1 (9->16, k=5, pad=2) + ReLU + MaxPool2 ----------
// x: fp32 [B][9][2048] -> y1: bf16 [B][16][1024]
__global__ __launch_bounds__(256) void conv1_pool(
    const float* __restrict__ x, const float* __restrict__ w,
    const float* __restrict__ bias, unsigned short* __restrict__ y1)
{
    __shared__ float xs[CIN][516];
    __shared__ float wT[CIN * 5 * 16];   // [cin][k][co]
    __shared__ float bls[16];
    const int tid = threadIdx.x;
    const int chunk = blockIdx.x;        // 0..3
    const int b = blockIdx.y;

    for (int idx = tid; idx < CIN * 5 * 16; idx += 256) {
        int co = idx / 45, rem = idx % 45;
        int ci = rem / 5, k = rem % 5;
        wT[(ci * 5 + k) * 16 + co] = w[idx];  // w layout [co][ci][k]
    }
    if (tid < 16) bls[tid] = bias[tid];

    const int t0 = chunk * 512;
    const float* xb = x + (size_t)b * CIN * T0_;
    for (int idx = tid; idx < CIN * 516; idx += 256) {
        int ci = idx / 516, j = idx % 516;
        int gt = t0 - 2 + j;
        xs[ci][j] = (gt >= 0 && gt < T0_) ? xb[ci * T0_ + gt] : 0.0f;
    }
    __syncthreads();

    float4 acc0[4] = {}; float4 acc1[4] = {};
    const int base = 2 * tid;
    for (int ci = 0; ci < CIN; ci++) {
        float xw[6];
        #pragma unroll
        for (int j = 0; j < 6; j++) xw[j] = xs[ci][base + j];
        #pragma unroll
        for (int k = 0; k < 5; k++) {
            const float4* wv4 = (const float4*)&wT[(ci * 5 + k) * 16];
            #pragma unroll
            for (int j = 0; j < 4; j++) {
                float4 wv = wv4[j];
                acc0[j].x += wv.x * xw[k];   acc0[j].y += wv.y * xw[k];
                acc0[j].z += wv.z * xw[k];   acc0[j].w += wv.w * xw[k];
                acc1[j].x += wv.x * xw[k+1]; acc1[j].y += wv.y * xw[k+1];
                acc1[j].z += wv.z * xw[k+1]; acc1[j].w += wv.w * xw[k+1];
            }
        }
    }
    const int tp = chunk * 256 + tid;
    unsigned short* yb = y1 + ((size_t)b * C1_) * T1_ + tp;
    #pragma unroll
    for (int j = 0; j < 4; j++) {
        float4 m = max4(acc0[j], acc1[j]);
        const float4 bv = *(const float4*)&bls[4 * j];
        yb[(4*j+0) * T1_] = f2bf(fmaxf(m.x + bv.x, 0.f));
        yb[(4*j+1) * T1_] = f2bf(fmaxf(m.y + bv.y, 0.f));
        yb[(4*j+2) * T1_] = f2bf(fmaxf(m.z + bv.z, 0.f));
        yb[(4*j+3) * T1_] = f2bf(fmaxf(m.w + bv.w, 0.f));
    }
}

// ---------- kernel 2: conv2 (16->32) + ReLU + MaxPool2, writes node-major ----------
// y1: bf16 [B][16][1024] -> y2t: bf16 [B*512][32]
__global__ __launch_bounds__(256) void conv2_pool(
    const unsigned short* __restrict__ y1, const float* __restrict__ w,
    const float* __restrict__ bias, unsigned short* __restrict__ y2t)
{
    __shared__ float xs[C1_][516];
    __shared__ float wT[C1_ * 5 * 32];   // [cin][k][co]
    __shared__ float bls[32];
    const int tid = threadIdx.x;
    const int chunk = blockIdx.x;        // 0..1
    const int b = blockIdx.y;

    for (int idx = tid; idx < C1_ * 5 * 32; idx += 256) {
        int co = idx / 80, rem = idx % 80;
        int ci = rem / 5, k = rem % 5;
        wT[(ci * 5 + k) * 32 + co] = w[idx];  // w layout [co][ci][k]
    }
    if (tid < 32) bls[tid] = bias[tid];

    const int t0 = chunk * 512;
    const unsigned short* xb = y1 + (size_t)b * C1_ * T1_;
    for (int idx = tid; idx < C1_ * 516; idx += 256) {
        int ci = idx / 516, j = idx % 516;
        int gt = t0 - 2 + j;
        xs[ci][j] = (gt >= 0 && gt < T1_) ? bf2f(xb[ci * T1_ + gt]) : 0.0f;
    }
    __syncthreads();

    float4 acc0[8] = {}; float4 acc1[8] = {};
    const int base = 2 * tid;
    for (int ci = 0; ci < C1_; ci++) {
        float xw[6];
        #pragma unroll
        for (int j = 0; j < 6; j++) xw[j] = xs[ci][base + j];
        #pragma unroll
        for (int k = 0; k < 5; k++) {
            const float4* wv4 = (const float4*)&wT[(ci * 5 + k) * 32];
            #pragma unroll
            for (int j = 0; j < 8; j++) {
                float4 wv = wv4[j];
                acc0[j].x += wv.x * xw[k];   acc0[j].y += wv.y * xw[k];
                acc0[j].z += wv.z * xw[k];   acc0[j].w += wv.w * xw[k];
                acc1[j].x += wv.x * xw[k+1]; acc1[j].y += wv.y * xw[k+1];
                acc1[j].z += wv.z * xw[k+1]; acc1[j].w += wv.w * xw[k+1];
            }
        }
    }
    const int tp = chunk * 256 + tid;               // 0..511
    const size_t n = (size_t)b * RT_ + tp;
    unsigned short* row = y2t + n * 32;
    #pragma unroll
    for (int j = 0; j < 8; j++) {
        float4 m = max4(acc0[j], acc1[j]);
        const float4 bv = *(const float4*)&bls[4 * j];
        m.x = fmaxf(m.x + bv.x, 0.f); m.y = fmaxf(m.y + bv.y, 0.f);
        m.z = fmaxf(m.z + bv.z, 0.f); m.w = fmaxf(m.w + bv.w, 0.f);
        st_bf16x4(row + 4 * j, m);
    }
}

// ---------- kernel R: repack W1, W2 (fp32) into bf16 MFMA fragment order ----------
// Wb1 frag layout (A-operand of gcn1, W1^T): [ft][lane][j]  (8 frags, K=32)
//   value = W1[k=quad*8+j][f=ft*16+(lane&15)],  quad = lane>>4
// Wb2 frag layout (B-operand of gcn2): [ks][ct][lane][j]  (32 frags, K=128)
//   value = W2[k=ks*32+quad*8+j][f=ct*16+(lane&15)]
__global__ __launch_bounds__(256) void repack_w(
    const float* __restrict__ W1, const float* __restrict__ W2,
    unsigned short* __restrict__ Wb1, unsigned short* __restrict__ Wb2)
{
    const int tid = threadIdx.x;
    for (int e = tid; e < 8 * 64 * 8; e += 256) {
        int j = e & 7, lane = (e >> 3) & 63, ft = e >> 9;
        int k = (lane >> 4) * 8 + j, f = ft * 16 + (lane & 15);
        Wb1[e] = f2bf(W1[k * 128 + f]);
    }
    for (int e = tid; e < 4 * 8 * 64 * 8; e += 256) {
        int j = e & 7, lane = (e >> 3) & 63, ct = (e >> 9) & 7, ks = e >> 12;
        int k = ks * 32 + (lane >> 4) * 8 + j, f = ct * 16 + (lane & 15);
        Wb2[e] = f2bf(W2[k * 128 + f]);
    }
}

// ---------- kernel 3: GCN1 via MFMA ----------
// h1[node][feat] = relu(stencil(y2t) @ W1 + b1), computed as D[f][n] = W1^T · A^T
// so each lane's 4 accs are 4 consecutive features of one node -> ushort4 stores.
__global__ __launch_bounds__(256) void gcn1_mfma(
    const unsigned short* __restrict__ X,    // y2t [N][32] bf16
    const unsigned short* __restrict__ Wb,   // Wb1 frags
    const float* __restrict__ bias,          // [128] fp32
    unsigned short* __restrict__ H1)         // [N][128] bf16
{
    __shared__ unsigned short A1[128 * 40];  // [node][feat32], row stride 40 (80B, 16B-aligned, 2-way bank)
    __shared__ float bls[128];
    const int tid = threadIdx.x;
    const int n0 = blockIdx.x * 128, r0 = n0 & (RT_ - 1);
    if (tid < 128) bls[tid] = bias[tid];

    {   // stage A = stencil(y2t) as bf16: thread t -> row t>>1, feat-half (t&1)*16
        const int row = tid >> 1, fh = (tid & 1) * 16;
        const int r = r0 + row, n = n0 + row;
        const float dm = dinv_of(r), cm = dm * dm;
        const unsigned short* Xc = X + (size_t)n * 32 + fh;
        us8 c0 = *(const us8*)(Xc), c1 = *(const us8*)(Xc + 8);
        float v[16];
        #pragma unroll
        for (int j = 0; j < 8; j++) { v[j] = cm * bf2f(c0[j]); v[8 + j] = cm * bf2f(c1[j]); }
        if (r > 0) {
            const float cl = dm * dinv_of(r - 1);
            us8 a0 = *(const us8*)(Xc - 32), a1 = *(const us8*)(Xc - 24);
            #pragma unroll
            for (int j = 0; j < 8; j++) { v[j] += cl * bf2f(a0[j]); v[8 + j] += cl * bf2f(a1[j]); }
        }
        if (r < RT_ - 1) {
            const float cr = dm * dinv_of(r + 1);
            us8 a0 = *(const us8*)(Xc + 32), a1 = *(const us8*)(Xc + 40);
            #pragma unroll
            for (int j = 0; j < 8; j++) { v[j] += cr * bf2f(a0[j]); v[8 + j] += cr * bf2f(a1[j]); }
        }
        us8 o0, o1;
        #pragma unroll
        for (int j = 0; j < 8; j++) { o0[j] = f2bf(v[j]); o1[j] = f2bf(v[8 + j]); }
        *(us8*)(&A1[row * 40 + fh]) = o0;
        *(us8*)(&A1[row * 40 + fh + 8]) = o1;
    }
    __syncthreads();

    const int lane = tid & 63, wave = tid >> 6;
    const int m = lane & 15, q = lane >> 4;
    bf16x8 wf[8];
    #pragma unroll
    for (int ft = 0; ft < 8; ft++) wf[ft] = *(const bf16x8*)(Wb + (ft * 64 + lane) * 8);
    bf16x8 bfr[2];
    #pragma unroll
    for (int i = 0; i < 2; i++) {
        int nt = wave * 2 + i;
        bfr[i] = *(const bf16x8*)(&A1[(nt * 16 + m) * 40 + q * 8]);
    }
    f32x4 acc[8][2] = {};
    #pragma unroll
    for (int ft = 0; ft < 8; ft++)
        #pragma unroll
        for (int i = 0; i < 2; i++)
            acc[ft][i] = __builtin_amdgcn_mfma_f32_16x16x32_bf16(wf[ft], bfr[i], acc[ft][i], 0, 0, 0);

    #pragma unroll
    for (int ft = 0; ft < 8; ft++) {
        const f32x4 bv = *(const f32x4*)&bls[ft * 16 + q * 4];
        #pragma unroll
        for (int i = 0; i < 2; i++) {
            int node = n0 + (wave * 2 + i) * 16 + m;
            ushort4 o;
            o.x = f2bf(fmaxf(acc[ft][i][0] + bv[0], 0.f));
            o.y = f2bf(fmaxf(acc[ft][i][1] + bv[1], 0.f));
            o.z = f2bf(fmaxf(acc[ft][i][2] + bv[2], 0.f));
            o.w = f2bf(fmaxf(acc[ft][i][3] + bv[3], 0.f));
            *(ushort4*)(H1 + (size_t)node * 128 + ft * 16 + q * 4) = o;
        }
    }
}

// ---------- kernel 4: GCN2 via MFMA + fused mean partials ----------
__global__ __launch_bounds__(256) void gcn2_mfma(
    const unsigned short* __restrict__ H1,   // [N][128] bf16
    const unsigned short* __restrict__ Wb,   // Wb2 frags
    const float* __restrict__ bias,          // [128]
    float* __restrict__ partials)            // [B][4][128] fp32
{
    __shared__ unsigned short A2[128 * 136]; // [node][feat], stride 136 (272B, 16B-aligned, 2-way bank)
    __shared__ float bls[128];
    const int tid = threadIdx.x;
    const int n0 = blockIdx.x * 128, r0 = n0 & (RT_ - 1);
    if (tid < 128) bls[tid] = bias[tid];

    {   // stage A = stencil(h1) as bf16: thread t -> row t>>1, feat-half (t&1)*64
        const int row = tid >> 1, fh = (tid & 1) * 64;
        const int r = r0 + row, n = n0 + row;
        const float dm = dinv_of(r), cm = dm * dm;
        const bool hasl = (r > 0), hasr = (r < RT_ - 1);
        const float cl = hasl ? dm * dinv_of(r - 1) : 0.f;
        const float cr = hasr ? dm * dinv_of(r + 1) : 0.f;
        const unsigned short* Xc = H1 + (size_t)n * 128 + fh;
        #pragma unroll
        for (int c = 0; c < 8; c++) {
            us8 cc = *(const us8*)(Xc + c * 8);
            float v[8];
            #pragma unroll
            for (int j = 0; j < 8; j++) v[j] = cm * bf2f(cc[j]);
            if (hasl) {
                us8 a = *(const us8*)(Xc - 128 + c * 8);
                #pragma unroll
                for (int j = 0; j < 8; j++) v[j] += cl * bf2f(a[j]);
            }
            if (hasr) {
                us8 a = *(const us8*)(Xc + 128 + c * 8);
                #pragma unroll
                for (int j = 0; j < 8; j++) v[j] += cr * bf2f(a[j]);
            }
            us8 o;
            #pragma unroll
            for (int j = 0; j < 8; j++) o[j] = f2bf(v[j]);
            *(us8*)(&A2[row * 136 + fh + c * 8]) = o;
        }
    }
    __syncthreads();

    const int lane = tid & 63, wave = tid >> 6;
    const int m = lane & 15, q = lane >> 4;
    bf16x8 bw[4][2];
    #pragma unroll
    for (int ks = 0; ks < 4; ks++)
        #pragma unroll
        for (int i = 0; i < 2; i++) {
            int ct = wave * 2 + i;
            bw[ks][i] = *(const bf16x8*)(Wb + ((size_t)((ks * 8 + ct) * 64 + lane)) * 8);
        }
    f32x4 acc[8][2] = {};
    for (int ks = 0; ks < 4; ks++) {
        #pragma unroll
        for (int nt = 0; nt < 8; nt++) {
            bf16x8 af = *(const bf16x8*)(&A2[(nt * 16 + m) * 136 + ks * 32 + q * 8]);
            acc[nt][0] = __builtin_amdgcn_mfma_f32_16x16x32_bf16(af, bw[ks][0], acc[nt][0], 0, 0, 0);
            acc[nt][1] = __builtin_amdgcn_mfma_f32_16x16x32_bf16(af, bw[ks][1], acc[nt][1], 0, 0, 0);
        }
    }
    // epilogue: bias+relu per element, sum over the tile's 128 rows (nodes)
    const float b0 = bls[wave * 32 + m];
    const float b1 = bls[wave * 32 + 16 + m];
    float s0 = 0.f, s1 = 0.f;
    #pragma unroll
    for (int nt = 0; nt < 8; nt++)
        #pragma unroll
        for (int rgi = 0; rgi < 4; rgi++) {
            s0 += fmaxf(acc[nt][0][rgi] + b0, 0.f);
            s1 += fmaxf(acc[nt][1][rgi] + b1, 0.f);
        }
    s0 += __shfl_xor(s0, 16, 64); s0 += __shfl_xor(s0, 32, 64);
    s1 += __shfl_xor(s1, 16, 64); s1 += __shfl_xor(s1, 32, 64);
    if (lane < 16) {
        const int batch = n0 >> 9, tile = (n0 >> 7) & 3;
        float* p = partials + ((batch << 2) + tile) * 128 + wave * 32;
        p[m] = s0;
        p[16 + m] = s1;
    }
}

// ---------- kernel 5: mean over RT + FC ----------
__global__ __launch_bounds__(128) void fc_kernel(
    const float* __restrict__ partials, const float* __restrict__ fw,
    const float* __restrict__ fb, float* __restrict__ out)
{
    __shared__ float sm[128];
    const int b = blockIdx.x, tid = threadIdx.x;
    float s = 0.f;
    #pragma unroll
    for (int t = 0; t < 4; t++) s += partials[((b << 2) + t) * 128 + tid];
    sm[tid] = s * (1.0f / 512.0f);
    __syncthreads();
    if (tid < 64) {
        float acc = fb[tid];
        #pragma unroll 8
        for (int f = 0; f < 128; f++) acc += sm[f] * fw[f * 64 + tid];
        out[b * 64 + tid] = acc;
    }
}

extern "C" void kernel_launch(void* const* d_in, const int* in_sizes, int n_in,
                              void* d_out, int out_size, void* d_ws, size_t ws_size,
                              hipStream_t stream)
{
    const float* x   = (const float*)d_in[0];
    const float* w1  = (const float*)d_in[1];
    const float* b1  = (const float*)d_in[2];
    const float* w2  = (const float*)d_in[3];
    const float* b2  = (const float*)d_in[4];
    const float* g1w = (const float*)d_in[5];
    const float* g1b = (const float*)d_in[6];
    const float* g2w = (const float*)d_in[7];
    const float* g2b = (const float*)d_in[8];
    const float* fw  = (const float*)d_in[9];
    const float* fb  = (const float*)d_in[10];

    char* ws = (char*)d_ws;
    // Layout: y1 bf16 32MB @0, y2t bf16 32MB @32MB, h1 bf16 128MB @64MB, partials 2MB @192MB.
    // Wb1 (8KB) / Wb2 (32KB) live inside the y1 region: y1 is dead after conv2_pool,
    // and repack_w launches after conv2_pool in stream order.
    unsigned short* y1  = (unsigned short*)(ws);
    unsigned short* y2t = (unsigned short*)(ws + (size_t)32 * 1024 * 1024);
    unsigned short* h1  = (unsigned short*)(ws + (size_t)64 * 1024 * 1024);
    float* partials     = (float*)(ws + (size_t)192 * 1024 * 1024);
    unsigned short* Wb1 = (unsigned short*)(ws);                 // 4096 elems
    unsigned short* Wb2 = (unsigned short*)(ws + 64 * 1024);     // 16384 elems
    float* out = (float*)d_out;

    conv1_pool<<<dim3(4, B_), 256, 0, stream>>>(x, w1, b1, y1);
    conv2_pool<<<dim3(2, B_), 256, 0, stream>>>(y1, w2, b2, y2t);
    repack_w<<<1, 256, 0, stream>>>(g1w, g2w, Wb1, Wb2);
    gcn1_mfma<<<NNODES / 128, 256, 0, stream>>>(y2t, Wb1, g1b, h1);
    gcn2_mfma<<<NNODES / 128, 256, 0, stream>>>(h1, Wb2, g2b, partials);
    fc_kernel<<<B_, 128, 0, stream>>>(partials, fw, fb, out);
}

// Round 4
// 365.927 us; speedup vs baseline: 1.6871x; 1.2564x over previous
//
#include <hip/hip_runtime.h>
#include <hip/hip_bf16.h>

// Problem constants
#define B_      1024
#define CIN     9
#define T0_     2048
#define C1_     16
#define T1_     1024
#define C2_     32
#define RT_     512
#define NNODES  (B_ * RT_)     // 524288
#define HID_    128
#define OUTF_   64

typedef __attribute__((ext_vector_type(8))) __bf16 bf16x8;
typedef __attribute__((ext_vector_type(4))) float f32x4;
typedef __attribute__((ext_vector_type(8))) unsigned short us8;

// ---------- helpers ----------
__device__ __forceinline__ float bf2f(unsigned short u) {
    union { unsigned int i; float f; } c; c.i = ((unsigned int)u) << 16; return c.f;
}
__device__ __forceinline__ unsigned short f2bf(float f) {
    union { float f; unsigned int i; } c; c.f = f;
    unsigned int i = c.i + 0x7FFFu + ((c.i >> 16) & 1u);  // round-nearest-even
    return (unsigned short)(i >> 16);
}
__device__ __forceinline__ float4 max4(float4 a, float4 b) {
    float4 v; v.x = fmaxf(a.x, b.x); v.y = fmaxf(a.y, b.y);
    v.z = fmaxf(a.z, b.z); v.w = fmaxf(a.w, b.w); return v;
}
__device__ __forceinline__ float dinv_of(int r) {
    return (r == 0 || r == RT_ - 1) ? 0.70710678118f : 0.57735026919f;
}

// ---------- kernel 1: conv1 (9->16, k=5, pad=2) + ReLU + MaxPool2 ----------
// x: fp32 [B][9][2048] -> y1: bf16 [B][16][1024]
__global__ __launch_bounds__(256) void conv1_pool(
    const float* __restrict__ x, const float* __restrict__ w,
    const float* __restrict__ bias, unsigned short* __restrict__ y1)
{
    __shared__ float xs[CIN][516];
    __shared__ float wT[CIN * 5 * 16];   // [cin][k][co]
    __shared__ float bls[16];
    const int tid = threadIdx.x;
    const int chunk = blockIdx.x;        // 0..3
    const int b = blockIdx.y;

    for (int idx = tid; idx < CIN * 5 * 16; idx += 256) {
        int co = idx / 45, rem = idx % 45;
        int ci = rem / 5, k = rem % 5;
        wT[(ci * 5 + k) * 16 + co] = w[idx];  // w layout [co][ci][k]
    }
    if (tid < 16) bls[tid] = bias[tid];

    const int t0 = chunk * 512;
    const float* xb = x + (size_t)b * CIN * T0_;
    for (int idx = tid; idx < CIN * 516; idx += 256) {
        int ci = idx / 516, j = idx % 516;
        int gt = t0 - 2 + j;
        xs[ci][j] = (gt >= 0 && gt < T0_) ? xb[ci * T0_ + gt] : 0.0f;
    }
    __syncthreads();

    float4 acc0[4] = {}; float4 acc1[4] = {};
    const int base = 2 * tid;
    for (int ci = 0; ci < CIN; ci++) {
        float xw[6];
        #pragma unroll
        for (int j = 0; j < 6; j++) xw[j] = xs[ci][base + j];
        #pragma unroll
        for (int k = 0; k < 5; k++) {
            const float4* wv4 = (const float4*)&wT[(ci * 5 + k) * 16];
            #pragma unroll
            for (int j = 0; j < 4; j++) {
                float4 wv = wv4[j];
                acc0[j].x += wv.x * xw[k];   acc0[j].y += wv.y * xw[k];
                acc0[j].z += wv.z * xw[k];   acc0[j].w += wv.w * xw[k];
                acc1[j].x += wv.x * xw[k+1]; acc1[j].y += wv.y * xw[k+1];
                acc1[j].z += wv.z * xw[k+1]; acc1[j].w += wv.w * xw[k+1];
            }
        }
    }
    const int tp = chunk * 256 + tid;
    unsigned short* yb = y1 + ((size_t)b * C1_) * T1_ + tp;
    #pragma unroll
    for (int j = 0; j < 4; j++) {
        float4 m = max4(acc0[j], acc1[j]);
        const float4 bv = *(const float4*)&bls[4 * j];
        yb[(4*j+0) * T1_] = f2bf(fmaxf(m.x + bv.x, 0.f));
        yb[(4*j+1) * T1_] = f2bf(fmaxf(m.y + bv.y, 0.f));
        yb[(4*j+2) * T1_] = f2bf(fmaxf(m.z + bv.z, 0.f));
        yb[(4*j+3) * T1_] = f2bf(fmaxf(m.w + bv.w, 0.f));
    }
}

// ---------- kernel 2: conv2 (16->32) + ReLU + MaxPool2, writes node-major ----------
// y1: bf16 [B][16][1024] -> y2t: bf16 [B*512][32]
__global__ __launch_bounds__(256) void conv2_pool(
    const unsigned short* __restrict__ y1, const float* __restrict__ w,
    const float* __restrict__ bias, unsigned short* __restrict__ y2t)
{
    __shared__ float xs[C1_][516];
    __shared__ float wT[C1_ * 5 * 32];   // [cin][k][co]
    __shared__ float bls[32];
    const int tid = threadIdx.x;
    const int chunk = blockIdx.x;        // 0..1
    const int b = blockIdx.y;

    for (int idx = tid; idx < C1_ * 5 * 32; idx += 256) {
        int co = idx / 80, rem = idx % 80;
        int ci = rem / 5, k = rem % 5;
        wT[(ci * 5 + k) * 32 + co] = w[idx];  // w layout [co][ci][k]
    }
    if (tid < 32) bls[tid] = bias[tid];

    const int t0 = chunk * 512;
    const unsigned short* xb = y1 + (size_t)b * C1_ * T1_;
    for (int idx = tid; idx < C1_ * 516; idx += 256) {
        int ci = idx / 516, j = idx % 516;
        int gt = t0 - 2 + j;
        xs[ci][j] = (gt >= 0 && gt < T1_) ? bf2f(xb[ci * T1_ + gt]) : 0.0f;
    }
    __syncthreads();

    float4 acc0[8] = {}; float4 acc1[8] = {};
    const int base = 2 * tid;
    for (int ci = 0; ci < C1_; ci++) {
        float xw[6];
        #pragma unroll
        for (int j = 0; j < 6; j++) xw[j] = xs[ci][base + j];
        #pragma unroll
        for (int k = 0; k < 5; k++) {
            const float4* wv4 = (const float4*)&wT[(ci * 5 + k) * 32];
            #pragma unroll
            for (int j = 0; j < 8; j++) {
                float4 wv = wv4[j];
                acc0[j].x += wv.x * xw[k];   acc0[j].y += wv.y * xw[k];
                acc0[j].z += wv.z * xw[k];   acc0[j].w += wv.w * xw[k];
                acc1[j].x += wv.x * xw[k+1]; acc1[j].y += wv.y * xw[k+1];
                acc1[j].z += wv.z * xw[k+1]; acc1[j].w += wv.w * xw[k+1];
            }
        }
    }
    const int tp = chunk * 256 + tid;               // 0..511
    const size_t n = (size_t)b * RT_ + tp;
    unsigned short* row = y2t + n * 32;
    #pragma unroll
    for (int j = 0; j < 8; j++) {
        float4 m = max4(acc0[j], acc1[j]);
        const float4 bv = *(const float4*)&bls[4 * j];
        m.x = fmaxf(m.x + bv.x, 0.f); m.y = fmaxf(m.y + bv.y, 0.f);
        m.z = fmaxf(m.z + bv.z, 0.f); m.w = fmaxf(m.w + bv.w, 0.f);
        ushort4 u; u.x = f2bf(m.x); u.y = f2bf(m.y); u.z = f2bf(m.z); u.w = f2bf(m.w);
        *(ushort4*)(row + 4 * j) = u;
    }
}

// ---------- kernel R: repack W1, W2 (fp32) into bf16 MFMA fragment order ----------
// Wb1 (A-operand of gcn1, W1^T): [ft][lane][j]: W1[k=quad*8+j][f=ft*16+(lane&15)]
// Wb2 (B-operand of gcn2): [ks][ct][lane][j]: W2[k=ks*32+quad*8+j][f=ct*16+(lane&15)]
__global__ __launch_bounds__(256) void repack_w(
    const float* __restrict__ W1, const float* __restrict__ W2,
    unsigned short* __restrict__ Wb1, unsigned short* __restrict__ Wb2)
{
    const int tid = threadIdx.x;
    if (blockIdx.x == 0) {
        for (int e = tid; e < 8 * 64 * 8; e += 256) {
            int j = e & 7, lane = (e >> 3) & 63, ft = e >> 9;
            int k = (lane >> 4) * 8 + j, f = ft * 16 + (lane & 15);
            Wb1[e] = f2bf(W1[k * 128 + f]);
        }
    } else {
        for (int e = tid; e < 4 * 8 * 64 * 8; e += 256) {
            int j = e & 7, lane = (e >> 3) & 63, ct = (e >> 9) & 7, ks = e >> 12;
            int k = ks * 32 + (lane >> 4) * 8 + j, f = ct * 16 + (lane & 15);
            Wb2[e] = f2bf(W2[k * 128 + f]);
        }
    }
}

// ---------- kernel 3: FUSED GCN1+GCN2 per 128-node tile; h1 never leaves LDS ----------
// Step 1: A1 = stencil(y2t) for 130 rows (halo ±1, batch-edge masked) -> LDS
// Step 2: H = relu(A1 @ W1 + b1) via MFMA -> LDS (halo rows recomputed exactly)
// Step 3: A2 = stencil(H) for 128 rows -> LDS (overlaps dead A1 region)
// Step 4: gcn2 MFMA + bias/relu + per-tile column sums -> partials
__global__ __launch_bounds__(256, 2) void gcn_fused(
    const unsigned short* __restrict__ X,    // y2t [N][32] bf16
    const unsigned short* __restrict__ Wb1,  // gcn1 W frags
    const unsigned short* __restrict__ Wb2,  // gcn2 W frags
    const float* __restrict__ b1,
    const float* __restrict__ b2,
    float* __restrict__ partials)            // [B][4][128] fp32
{
    // LDS plan (bytes):
    //   [0, 38912)     : A2, 128 rows * 152 shorts (stride 152 -> 2-way-only banks)
    //   [0, 11520)     : As1, 144 rows * 40 shorts (dead after step 2; A2 overlaps)
    //   [38912, 74272) : H, 130 rows * 136 shorts
    //   [74272, 74784) : bls1[128] fp32;  [74784, 75296): bls2[128] fp32
    __shared__ __align__(16) unsigned char lds[75296];
    unsigned short* As1 = (unsigned short*)lds;
    unsigned short* A2  = (unsigned short*)lds;
    unsigned short* H   = (unsigned short*)(lds + 38912);
    float* bls1 = (float*)(lds + 74272);
    float* bls2 = (float*)(lds + 74784);

    const int tid = threadIdx.x;
    const int n0 = blockIdx.x * 128, r0 = n0 & (RT_ - 1);
    if (tid < 128) { bls1[tid] = b1[tid]; bls2[tid] = b2[tid]; }

    // ---- step 1: A1 rows i=0..129 -> node n0-1+i, r=r0-1+i; rows 130..143 zeroed
    for (int s = tid; s < 288; s += 256) {
        const int i = s >> 1, fh = (s & 1) * 16;
        unsigned short* dst = As1 + i * 40 + fh;
        const int r = r0 - 1 + i;
        if (i >= 130 || r < 0 || r >= RT_) {
            us8 z;
            #pragma unroll
            for (int j = 0; j < 8; j++) z[j] = 0;
            *(us8*)dst = z; *(us8*)(dst + 8) = z;
        } else {
            const float dm = dinv_of(r), cm = dm * dm;
            const unsigned short* Xc = X + (size_t)(n0 - 1 + i) * 32 + fh;
            us8 c0 = *(const us8*)(Xc), c1 = *(const us8*)(Xc + 8);
            float v[16];
            #pragma unroll
            for (int j = 0; j < 8; j++) { v[j] = cm * bf2f(c0[j]); v[8 + j] = cm * bf2f(c1[j]); }
            if (r > 0) {
                const float cl = dm * dinv_of(r - 1);
                us8 a0 = *(const us8*)(Xc - 32), a1 = *(const us8*)(Xc - 24);
                #pragma unroll
                for (int j = 0; j < 8; j++) { v[j] += cl * bf2f(a0[j]); v[8 + j] += cl * bf2f(a1[j]); }
            }
            if (r < RT_ - 1) {
                const float cr = dm * dinv_of(r + 1);
                us8 a0 = *(const us8*)(Xc + 32), a1 = *(const us8*)(Xc + 40);
                #pragma unroll
                for (int j = 0; j < 8; j++) { v[j] += cr * bf2f(a0[j]); v[8 + j] += cr * bf2f(a1[j]); }
            }
            us8 o0, o1;
            #pragma unroll
            for (int j = 0; j < 8; j++) { o0[j] = f2bf(v[j]); o1[j] = f2bf(v[8 + j]); }
            *(us8*)dst = o0; *(us8*)(dst + 8) = o1;
        }
    }
    __syncthreads();

    const int lane = tid & 63, wave = tid >> 6;
    const int m = lane & 15, q = lane >> 4;

    // ---- step 2: gcn1 MFMA; wave handles feature-tiles {2w, 2w+1} x 9 node-tiles
    {
        const int ft0 = wave * 2;
        const bf16x8 wf0 = *(const bf16x8*)(Wb1 + (ft0 * 64 + lane) * 8);
        const bf16x8 wf1 = *(const bf16x8*)(Wb1 + ((ft0 + 1) * 64 + lane) * 8);
        const float4 bv0 = *(const float4*)&bls1[ft0 * 16 + q * 4];
        const float4 bv1 = *(const float4*)&bls1[(ft0 + 1) * 16 + q * 4];
        #pragma unroll
        for (int nt = 0; nt < 9; nt++) {
            const bf16x8 bfr = *(const bf16x8*)(As1 + (nt * 16 + m) * 40 + q * 8);
            f32x4 a0 = {}, a1 = {};
            a0 = __builtin_amdgcn_mfma_f32_16x16x32_bf16(wf0, bfr, a0, 0, 0, 0);
            a1 = __builtin_amdgcn_mfma_f32_16x16x32_bf16(wf1, bfr, a1, 0, 0, 0);
            const int row = nt * 16 + m;    // local h1 row (node n0-1+row)
            if (row < 130) {
                ushort4 o0, o1;
                o0.x = f2bf(fmaxf(a0[0] + bv0.x, 0.f));
                o0.y = f2bf(fmaxf(a0[1] + bv0.y, 0.f));
                o0.z = f2bf(fmaxf(a0[2] + bv0.z, 0.f));
                o0.w = f2bf(fmaxf(a0[3] + bv0.w, 0.f));
                o1.x = f2bf(fmaxf(a1[0] + bv1.x, 0.f));
                o1.y = f2bf(fmaxf(a1[1] + bv1.y, 0.f));
                o1.z = f2bf(fmaxf(a1[2] + bv1.z, 0.f));
                o1.w = f2bf(fmaxf(a1[3] + bv1.w, 0.f));
                *(ushort4*)(H + row * 136 + ft0 * 16 + q * 4) = o0;
                *(ushort4*)(H + row * 136 + (ft0 + 1) * 16 + q * 4) = o1;
            }
        }
    }
    __syncthreads();

    // ---- step 3: A2[j] = cm*H[j+1] + cl*H[j] + cr*H[j+2], j=0..127 (1 task/thread)
    {
        const int j = tid >> 1, fh = (tid & 1) * 64;
        const int r = r0 + j;
        const float dm = dinv_of(r), cm = dm * dm;
        const float cl = (r > 0) ? dm * dinv_of(r - 1) : 0.f;
        const float cr = (r < RT_ - 1) ? dm * dinv_of(r + 1) : 0.f;
        const unsigned short* Hl = H + j * 136 + fh;
        const unsigned short* Hc = Hl + 136;
        const unsigned short* Hr = Hc + 136;
        unsigned short* dst = A2 + j * 152 + fh;
        #pragma unroll
        for (int c = 0; c < 8; c++) {
            us8 cc = *(const us8*)(Hc + c * 8);
            us8 ll = *(const us8*)(Hl + c * 8);
            us8 rr = *(const us8*)(Hr + c * 8);
            us8 o;
            #pragma unroll
            for (int e = 0; e < 8; e++)
                o[e] = f2bf(cm * bf2f(cc[e]) + cl * bf2f(ll[e]) + cr * bf2f(rr[e]));
            *(us8*)(dst + c * 8) = o;
        }
    }
    __syncthreads();

    // ---- step 4: gcn2 MFMA + fused mean partials (layout verified in R3)
    bf16x8 bw[4][2];
    #pragma unroll
    for (int ks = 0; ks < 4; ks++)
        #pragma unroll
        for (int i = 0; i < 2; i++) {
            int ct = wave * 2 + i;
            bw[ks][i] = *(const bf16x8*)(Wb2 + ((size_t)((ks * 8 + ct) * 64 + lane)) * 8);
        }
    f32x4 acc[8][2] = {};
    #pragma unroll
    for (int ks = 0; ks < 4; ks++) {
        #pragma unroll
        for (int nt = 0; nt < 8; nt++) {
            const bf16x8 af = *(const bf16x8*)(A2 + (nt * 16 + m) * 152 + ks * 32 + q * 8);
            acc[nt][0] = __builtin_amdgcn_mfma_f32_16x16x32_bf16(af, bw[ks][0], acc[nt][0], 0, 0, 0);
            acc[nt][1] = __builtin_amdgcn_mfma_f32_16x16x32_bf16(af, bw[ks][1], acc[nt][1], 0, 0, 0);
        }
    }
    const float bb0 = bls2[wave * 32 + m];
    const float bb1 = bls2[wave * 32 + 16 + m];
    float s0 = 0.f, s1 = 0.f;
    #pragma unroll
    for (int nt = 0; nt < 8; nt++)
        #pragma unroll
        for (int rgi = 0; rgi < 4; rgi++) {
            s0 += fmaxf(acc[nt][0][rgi] + bb0, 0.f);
            s1 += fmaxf(acc[nt][1][rgi] + bb1, 0.f);
        }
    s0 += __shfl_xor(s0, 16, 64); s0 += __shfl_xor(s0, 32, 64);
    s1 += __shfl_xor(s1, 16, 64); s1 += __shfl_xor(s1, 32, 64);
    if (lane < 16) {
        const int batch = n0 >> 9, tile = (n0 >> 7) & 3;
        float* p = partials + ((batch << 2) + tile) * 128 + wave * 32;
        p[m] = s0;
        p[16 + m] = s1;
    }
}

// ---------- kernel 5: mean over RT + FC ----------
__global__ __launch_bounds__(128) void fc_kernel(
    const float* __restrict__ partials, const float* __restrict__ fw,
    const float* __restrict__ fb, float* __restrict__ out)
{
    __shared__ float sm[128];
    const int b = blockIdx.x, tid = threadIdx.x;
    float s = 0.f;
    #pragma unroll
    for (int t = 0; t < 4; t++) s += partials[((b << 2) + t) * 128 + tid];
    sm[tid] = s * (1.0f / 512.0f);
    __syncthreads();
    if (tid < 64) {
        float acc = fb[tid];
        #pragma unroll 8
        for (int f = 0; f < 128; f++) acc += sm[f] * fw[f * 64 + tid];
        out[b * 64 + tid] = acc;
    }
}

extern "C" void kernel_launch(void* const* d_in, const int* in_sizes, int n_in,
                              void* d_out, int out_size, void* d_ws, size_t ws_size,
                              hipStream_t stream)
{
    const float* x   = (const float*)d_in[0];
    const float* w1  = (const float*)d_in[1];
    const float* b1  = (const float*)d_in[2];
    const float* w2  = (const float*)d_in[3];
    const float* b2  = (const float*)d_in[4];
    const float* g1w = (const float*)d_in[5];
    const float* g1b = (const float*)d_in[6];
    const float* g2w = (const float*)d_in[7];
    const float* g2b = (const float*)d_in[8];
    const float* fw  = (const float*)d_in[9];
    const float* fb  = (const float*)d_in[10];

    char* ws = (char*)d_ws;
    // y1 bf16 32MB @0, y2t bf16 32MB @32MB, partials 2MB @192MB.
    // Wb1/Wb2 live inside the y1 region (y1 dead after conv2_pool; repack after it).
    unsigned short* y1  = (unsigned short*)(ws);
    unsigned short* y2t = (unsigned short*)(ws + (size_t)32 * 1024 * 1024);
    float* partials     = (float*)(ws + (size_t)192 * 1024 * 1024);
    unsigned short* Wb1 = (unsigned short*)(ws);                 // 4096 elems
    unsigned short* Wb2 = (unsigned short*)(ws + 64 * 1024);     // 16384 elems
    float* out = (float*)d_out;

    conv1_pool<<<dim3(4, B_), 256, 0, stream>>>(x, w1, b1, y1);
    conv2_pool<<<dim3(2, B_), 256, 0, stream>>>(y1, w2, b2, y2t);
    repack_w<<<2, 256, 0, stream>>>(g1w, g2w, Wb1, Wb2);
    gcn_fused<<<NNODES / 128, 256, 0, stream>>>(y2t, Wb1, Wb2, g1b, g2b, partials);
    fc_kernel<<<B_, 128, 0, stream>>>(partials, fw, fb, out);
}

// Round 5
// 228.079 us; speedup vs baseline: 2.7068x; 1.6044x over previous
//
#include <hip/hip_runtime.h>
#include <hip/hip_bf16.h>

// Problem constants
#define B_      1024
#define CIN     9
#define T0_     2048
#define C1_     16
#define T1_     1024
#define C2_     32
#define RT_     512
#define NNODES  (B_ * RT_)     // 524288
#define HID_    128
#define OUTF_   64

typedef __attribute__((ext_vector_type(8))) __bf16 bf16x8;
typedef __attribute__((ext_vector_type(4))) float f32x4;
typedef __attribute__((ext_vector_type(8))) unsigned short us8;

// ---------- helpers ----------
__device__ __forceinline__ float bf2f(unsigned short u) {
    union { unsigned int i; float f; } c; c.i = ((unsigned int)u) << 16; return c.f;
}
__device__ __forceinline__ unsigned short f2bf(float f) {
    union { float f; unsigned int i; } c; c.f = f;
    unsigned int i = c.i + 0x7FFFu + ((c.i >> 16) & 1u);  // round-nearest-even
    return (unsigned short)(i >> 16);
}
__device__ __forceinline__ float dinv_of(int r) {
    return (r == 0 || r == RT_ - 1) ? 0.70710678118f : 0.57735026919f;
}

// ---------- kernel R: repack all weights into bf16 MFMA fragment order ----------
// Convention (16x16x32): A-frag A[m=lane&15][k=(lane>>4)*8+j]; B-frag B[k=(lane>>4)*8+j][n=lane&15]
// Wb1 (A-op of gcn1, W1^T): [ft][lane][j] = W1[k=(lane>>4)*8+j][f=ft*16+(lane&15)]
// Wb2 (B-op of gcn2): [ks][ct][lane][j] = W2[k=ks*32+(lane>>4)*8+j][f=ct*16+(lane&15)]
// Wc1 (B-op of conv1): [ks][lane][j]: kk=ks*32+(lane>>4)*8+j -> k=kk>>4, ci=kk&15;
//     = (k<5 && ci<9) ? w1[co=lane&15][ci][k] : 0
// Wc2 (B-op of conv2): [ks][nt][lane][j]: co=nt*16+(lane&15); = (k<5) ? w2[co][ci][k] : 0
__global__ __launch_bounds__(256) void repack_w(
    const float* __restrict__ W1g, const float* __restrict__ W2g,
    const float* __restrict__ Wc1g, const float* __restrict__ Wc2g,
    unsigned short* __restrict__ Wb1, unsigned short* __restrict__ Wb2,
    unsigned short* __restrict__ Wc1, unsigned short* __restrict__ Wc2)
{
    const int tid = threadIdx.x;
    if (blockIdx.x == 0) {
        for (int e = tid; e < 8 * 64 * 8; e += 256) {
            int j = e & 7, lane = (e >> 3) & 63, ft = e >> 9;
            int k = (lane >> 4) * 8 + j, f = ft * 16 + (lane & 15);
            Wb1[e] = f2bf(W1g[k * 128 + f]);
        }
    } else if (blockIdx.x == 1) {
        for (int e = tid; e < 4 * 8 * 64 * 8; e += 256) {
            int j = e & 7, lane = (e >> 3) & 63, ct = (e >> 9) & 7, ks = e >> 12;
            int k = ks * 32 + (lane >> 4) * 8 + j, f = ct * 16 + (lane & 15);
            Wb2[e] = f2bf(W2g[k * 128 + f]);
        }
    } else if (blockIdx.x == 2) {
        for (int e = tid; e < 3 * 64 * 8; e += 256) {
            int j = e & 7, lane = (e >> 3) & 63, ks = e >> 9;
            int kk = ks * 32 + (lane >> 4) * 8 + j;
            int k = kk >> 4, ci = kk & 15, co = lane & 15;
            Wc1[e] = (k < 5 && ci < CIN) ? f2bf(Wc1g[(co * CIN + ci) * 5 + k]) : 0;
        }
    } else {
        for (int e = tid; e < 3 * 2 * 64 * 8; e += 256) {
            int j = e & 7, lane = (e >> 3) & 63, nt = (e >> 9) & 1, ks = e >> 10;
            int kk = ks * 32 + (lane >> 4) * 8 + j;
            int k = kk >> 4, ci = kk & 15, co = nt * 16 + (lane & 15);
            Wc2[e] = (k < 5) ? f2bf(Wc2g[(co * C1_ + ci) * 5 + k]) : 0;
        }
    }
}

// ---------- kernel 1: conv1 via MFMA (9->16, k=5, pad=2) + ReLU + MaxPool2 ----------
// x fp32 [B][9][2048] -> y1t bf16 [B][1024][16] (time-major)
// GEMM view: M = pre-pool t (1024/chunk), N = 16 co, K = 96 (k*16+ci, zero-padded)
__global__ __launch_bounds__(256) void conv1_mfma(
    const float* __restrict__ x, const unsigned short* __restrict__ Wc1,
    const float* __restrict__ bias, unsigned short* __restrict__ y1t)
{
    __shared__ unsigned short xs[1030 * 24];   // row stride 24 shorts: 16B-aligned, 2-way banks
    const int tid = threadIdx.x;
    const int chunk = blockIdx.x;              // 0..1
    const int b = blockIdx.y;
    const int t0 = chunk * 1024;
    const float* xb = x + (size_t)b * CIN * T0_;

    // stage rows s=0..1029: t = t0-2+s; xs[s][ci] bf16 (ci 9..15 zero); OOB t -> zero
    for (int s = tid; s < 1030; s += 256) {
        const int t = t0 - 2 + s;
        us8 o0, o1;
        if (t >= 0 && t < T0_) {
            #pragma unroll
            for (int ci = 0; ci < 8; ci++) o0[ci] = f2bf(xb[ci * T0_ + t]);
            o1[0] = f2bf(xb[8 * T0_ + t]);
            #pragma unroll
            for (int jj = 1; jj < 8; jj++) o1[jj] = 0;
        } else {
            #pragma unroll
            for (int jj = 0; jj < 8; jj++) { o0[jj] = 0; o1[jj] = 0; }
        }
        *(us8*)(xs + s * 24) = o0;
        *(us8*)(xs + s * 24 + 8) = o1;
    }
    __syncthreads();

    const int lane = tid & 63, wave = tid >> 6;
    const int m = lane & 15, q = lane >> 4;
    bf16x8 wf[3];
    #pragma unroll
    for (int ks = 0; ks < 3; ks++)
        wf[ks] = *(const bf16x8*)(Wc1 + (ks * 64 + lane) * 8);
    const float bv = bias[m];   // m = co in C-layout (col=lane&15)

    for (int i = 0; i < 16; i++) {
        const int mt = wave * 16 + i;
        f32x4 acc = {};
        #pragma unroll
        for (int ks = 0; ks < 3; ks++) {
            const int row = mt * 16 + m + ks * 2 + (q >> 1);
            const bf16x8 af = *(const bf16x8*)(xs + row * 24 + (q & 1) * 8);
            acc = __builtin_amdgcn_mfma_f32_16x16x32_bf16(af, wf[ks], acc, 0, 0, 0);
        }
        // lane holds D[t = mt*16 + q*4 + rgi][co=m]; bias+relu then pool rgi pairs
        const int tp = chunk * 512 + mt * 8 + q * 2;
        unsigned short* yr = y1t + ((size_t)b * 1024 + tp) * 16 + m;
        const float p0 = fmaxf(fmaxf(acc[0] + bv, 0.f), fmaxf(acc[1] + bv, 0.f));
        const float p1 = fmaxf(fmaxf(acc[2] + bv, 0.f), fmaxf(acc[3] + bv, 0.f));
        yr[0]  = f2bf(p0);
        yr[16] = f2bf(p1);
    }
}

// ---------- kernel 2: conv2 via MFMA (16->32) + ReLU + MaxPool2, node-major out ----------
// y1t bf16 [B][1024][16] -> y2t bf16 [B*512][32]
// GEMM view: M = pre-pool t (512/chunk), N = 32 co (2 n-tiles), K = 96
__global__ __launch_bounds__(256) void conv2_mfma(
    const unsigned short* __restrict__ y1t, const unsigned short* __restrict__ Wc2,
    const float* __restrict__ bias, unsigned short* __restrict__ y2t)
{
    __shared__ unsigned short ys[518 * 24];
    const int tid = threadIdx.x;
    const int chunk = blockIdx.x;              // 0..1
    const int b = blockIdx.y;
    const int t0 = chunk * 512;
    const unsigned short* yb = y1t + (size_t)b * 1024 * 16;

    for (int s = tid; s < 518; s += 256) {
        const int t1 = t0 - 2 + s;
        us8 o0, o1;
        if (t1 >= 0 && t1 < 1024) {
            o0 = *(const us8*)(yb + t1 * 16);
            o1 = *(const us8*)(yb + t1 * 16 + 8);
        } else {
            #pragma unroll
            for (int jj = 0; jj < 8; jj++) { o0[jj] = 0; o1[jj] = 0; }
        }
        *(us8*)(ys + s * 24) = o0;
        *(us8*)(ys + s * 24 + 8) = o1;
    }
    __syncthreads();

    const int lane = tid & 63, wave = tid >> 6;
    const int m = lane & 15, q = lane >> 4;
    bf16x8 wf[3][2];
    #pragma unroll
    for (int ks = 0; ks < 3; ks++)
        #pragma unroll
        for (int nt = 0; nt < 2; nt++)
            wf[ks][nt] = *(const bf16x8*)(Wc2 + ((ks * 2 + nt) * 64 + lane) * 8);
    const float bv0 = bias[m], bv1 = bias[16 + m];

    for (int i = 0; i < 8; i++) {
        const int mt = wave * 8 + i;
        f32x4 a0 = {}, a1 = {};
        #pragma unroll
        for (int ks = 0; ks < 3; ks++) {
            const int row = mt * 16 + m + ks * 2 + (q >> 1);
            const bf16x8 af = *(const bf16x8*)(ys + row * 24 + (q & 1) * 8);
            a0 = __builtin_amdgcn_mfma_f32_16x16x32_bf16(af, wf[ks][0], a0, 0, 0, 0);
            a1 = __builtin_amdgcn_mfma_f32_16x16x32_bf16(af, wf[ks][1], a1, 0, 0, 0);
        }
        const int node = chunk * 256 + mt * 8 + q * 2;
        unsigned short* orow = y2t + ((size_t)b * RT_ + node) * 32;
        orow[m]           = f2bf(fmaxf(fmaxf(a0[0] + bv0, 0.f), fmaxf(a0[1] + bv0, 0.f)));
        orow[32 + m]      = f2bf(fmaxf(fmaxf(a0[2] + bv0, 0.f), fmaxf(a0[3] + bv0, 0.f)));
        orow[16 + m]      = f2bf(fmaxf(fmaxf(a1[0] + bv1, 0.f), fmaxf(a1[1] + bv1, 0.f)));
        orow[32 + 16 + m] = f2bf(fmaxf(fmaxf(a1[2] + bv1, 0.f), fmaxf(a1[3] + bv1, 0.f)));
    }
}

// ---------- kernel 3: FUSED GCN1+GCN2 per 128-node tile; h1 never leaves HBM ----------
__global__ __launch_bounds__(256, 2) void gcn_fused(
    const unsigned short* __restrict__ X,    // y2t [N][32] bf16
    const unsigned short* __restrict__ Wb1,  // gcn1 W frags
    const unsigned short* __restrict__ Wb2,  // gcn2 W frags
    const float* __restrict__ b1,
    const float* __restrict__ b2,
    float* __restrict__ partials)            // [B][4][128] fp32
{
    // LDS plan (bytes):
    //   [0, 38912)     : A2, 128 rows * 152 shorts
    //   [0, 11520)     : As1, 144 rows * 40 shorts (dead after step 2; A2 overlaps)
    //   [38912, 74272) : H, 130 rows * 136 shorts
    //   [74272, 74784) : bls1[128] fp32;  [74784, 75296): bls2[128] fp32
    __shared__ __align__(16) unsigned char lds[75296];
    unsigned short* As1 = (unsigned short*)lds;
    unsigned short* A2  = (unsigned short*)lds;
    unsigned short* H   = (unsigned short*)(lds + 38912);
    float* bls1 = (float*)(lds + 74272);
    float* bls2 = (float*)(lds + 74784);

    const int tid = threadIdx.x;
    const int n0 = blockIdx.x * 128, r0 = n0 & (RT_ - 1);
    if (tid < 128) { bls1[tid] = b1[tid]; bls2[tid] = b2[tid]; }

    // ---- step 1: A1 rows i=0..129 -> node n0-1+i, r=r0-1+i; rows 130..143 zeroed
    for (int s = tid; s < 288; s += 256) {
        const int i = s >> 1, fh = (s & 1) * 16;
        unsigned short* dst = As1 + i * 40 + fh;
        const int r = r0 - 1 + i;
        if (i >= 130 || r < 0 || r >= RT_) {
            us8 z;
            #pragma unroll
            for (int j = 0; j < 8; j++) z[j] = 0;
            *(us8*)dst = z; *(us8*)(dst + 8) = z;
        } else {
            const float dm = dinv_of(r), cm = dm * dm;
            const unsigned short* Xc = X + (size_t)(n0 - 1 + i) * 32 + fh;
            us8 c0 = *(const us8*)(Xc), c1 = *(const us8*)(Xc + 8);
            float v[16];
            #pragma unroll
            for (int j = 0; j < 8; j++) { v[j] = cm * bf2f(c0[j]); v[8 + j] = cm * bf2f(c1[j]); }
            if (r > 0) {
                const float cl = dm * dinv_of(r - 1);
                us8 a0 = *(const us8*)(Xc - 32), a1 = *(const us8*)(Xc - 24);
                #pragma unroll
                for (int j = 0; j < 8; j++) { v[j] += cl * bf2f(a0[j]); v[8 + j] += cl * bf2f(a1[j]); }
            }
            if (r < RT_ - 1) {
                const float cr = dm * dinv_of(r + 1);
                us8 a0 = *(const us8*)(Xc + 32), a1 = *(const us8*)(Xc + 40);
                #pragma unroll
                for (int j = 0; j < 8; j++) { v[j] += cr * bf2f(a0[j]); v[8 + j] += cr * bf2f(a1[j]); }
            }
            us8 o0, o1;
            #pragma unroll
            for (int j = 0; j < 8; j++) { o0[j] = f2bf(v[j]); o1[j] = f2bf(v[8 + j]); }
            *(us8*)dst = o0; *(us8*)(dst + 8) = o1;
        }
    }
    __syncthreads();

    const int lane = tid & 63, wave = tid >> 6;
    const int m = lane & 15, q = lane >> 4;

    // ---- step 2: gcn1 MFMA; wave handles feature-tiles {2w, 2w+1} x 9 node-tiles
    {
        const int ft0 = wave * 2;
        const bf16x8 wf0 = *(const bf16x8*)(Wb1 + (ft0 * 64 + lane) * 8);
        const bf16x8 wf1 = *(const bf16x8*)(Wb1 + ((ft0 + 1) * 64 + lane) * 8);
        const float4 bv0 = *(const float4*)&bls1[ft0 * 16 + q * 4];
        const float4 bv1 = *(const float4*)&bls1[(ft0 + 1) * 16 + q * 4];
        #pragma unroll
        for (int nt = 0; nt < 9; nt++) {
            const bf16x8 bfr = *(const bf16x8*)(As1 + (nt * 16 + m) * 40 + q * 8);
            f32x4 a0 = {}, a1 = {};
            a0 = __builtin_amdgcn_mfma_f32_16x16x32_bf16(wf0, bfr, a0, 0, 0, 0);
            a1 = __builtin_amdgcn_mfma_f32_16x16x32_bf16(wf1, bfr, a1, 0, 0, 0);
            const int row = nt * 16 + m;    // local h1 row (node n0-1+row)
            if (row < 130) {
                ushort4 o0, o1;
                o0.x = f2bf(fmaxf(a0[0] + bv0.x, 0.f));
                o0.y = f2bf(fmaxf(a0[1] + bv0.y, 0.f));
                o0.z = f2bf(fmaxf(a0[2] + bv0.z, 0.f));
                o0.w = f2bf(fmaxf(a0[3] + bv0.w, 0.f));
                o1.x = f2bf(fmaxf(a1[0] + bv1.x, 0.f));
                o1.y = f2bf(fmaxf(a1[1] + bv1.y, 0.f));
                o1.z = f2bf(fmaxf(a1[2] + bv1.z, 0.f));
                o1.w = f2bf(fmaxf(a1[3] + bv1.w, 0.f));
                *(ushort4*)(H + row * 136 + ft0 * 16 + q * 4) = o0;
                *(ushort4*)(H + row * 136 + (ft0 + 1) * 16 + q * 4) = o1;
            }
        }
    }
    __syncthreads();

    // ---- step 3: A2[j] = cm*H[j+1] + cl*H[j] + cr*H[j+2], j=0..127
    {
        const int j = tid >> 1, fh = (tid & 1) * 64;
        const int r = r0 + j;
        const float dm = dinv_of(r), cm = dm * dm;
        const float cl = (r > 0) ? dm * dinv_of(r - 1) : 0.f;
        const float cr = (r < RT_ - 1) ? dm * dinv_of(r + 1) : 0.f;
        const unsigned short* Hl = H + j * 136 + fh;
        const unsigned short* Hc = Hl + 136;
        const unsigned short* Hr = Hc + 136;
        unsigned short* dst = A2 + j * 152 + fh;
        #pragma unroll
        for (int c = 0; c < 8; c++) {
            us8 cc = *(const us8*)(Hc + c * 8);
            us8 ll = *(const us8*)(Hl + c * 8);
            us8 rr = *(const us8*)(Hr + c * 8);
            us8 o;
            #pragma unroll
            for (int e = 0; e < 8; e++)
                o[e] = f2bf(cm * bf2f(cc[e]) + cl * bf2f(ll[e]) + cr * bf2f(rr[e]));
            *(us8*)(dst + c * 8) = o;
        }
    }
    __syncthreads();

    // ---- step 4: gcn2 MFMA + fused mean partials
    bf16x8 bw[4][2];
    #pragma unroll
    for (int ks = 0; ks < 4; ks++)
        #pragma unroll
        for (int i = 0; i < 2; i++) {
            int ct = wave * 2 + i;
            bw[ks][i] = *(const bf16x8*)(Wb2 + ((size_t)((ks * 8 + ct) * 64 + lane)) * 8);
        }
    f32x4 acc[8][2] = {};
    #pragma unroll
    for (int ks = 0; ks < 4; ks++) {
        #pragma unroll
        for (int nt = 0; nt < 8; nt++) {
            const bf16x8 af = *(const bf16x8*)(A2 + (nt * 16 + m) * 152 + ks * 32 + q * 8);
            acc[nt][0] = __builtin_amdgcn_mfma_f32_16x16x32_bf16(af, bw[ks][0], acc[nt][0], 0, 0, 0);
            acc[nt][1] = __builtin_amdgcn_mfma_f32_16x16x32_bf16(af, bw[ks][1], acc[nt][1], 0, 0, 0);
        }
    }
    const float bb0 = bls2[wave * 32 + m];
    const float bb1 = bls2[wave * 32 + 16 + m];
    float s0 = 0.f, s1 = 0.f;
    #pragma unroll
    for (int nt = 0; nt < 8; nt++)
        #pragma unroll
        for (int rgi = 0; rgi < 4; rgi++) {
            s0 += fmaxf(acc[nt][0][rgi] + bb0, 0.f);
            s1 += fmaxf(acc[nt][1][rgi] + bb1, 0.f);
        }
    s0 += __shfl_xor(s0, 16, 64); s0 += __shfl_xor(s0, 32, 64);
    s1 += __shfl_xor(s1, 16, 64); s1 += __shfl_xor(s1, 32, 64);
    if (lane < 16) {
        const int batch = n0 >> 9, tile = (n0 >> 7) & 3;
        float* p = partials + ((batch << 2) + tile) * 128 + wave * 32;
        p[m] = s0;
        p[16 + m] = s1;
    }
}

// ---------- kernel 5: mean over RT + FC ----------
__global__ __launch_bounds__(128) void fc_kernel(
    const float* __restrict__ partials, const float* __restrict__ fw,
    const float* __restrict__ fb, float* __restrict__ out)
{
    __shared__ float sm[128];
    const int b = blockIdx.x, tid = threadIdx.x;
    float s = 0.f;
    #pragma unroll
    for (int t = 0; t < 4; t++) s += partials[((b << 2) + t) * 128 + tid];
    sm[tid] = s * (1.0f / 512.0f);
    __syncthreads();
    if (tid < 64) {
        float acc = fb[tid];
        #pragma unroll 8
        for (int f = 0; f < 128; f++) acc += sm[f] * fw[f * 64 + tid];
        out[b * 64 + tid] = acc;
    }
}

extern "C" void kernel_launch(void* const* d_in, const int* in_sizes, int n_in,
                              void* d_out, int out_size, void* d_ws, size_t ws_size,
                              hipStream_t stream)
{
    const float* x   = (const float*)d_in[0];
    const float* w1  = (const float*)d_in[1];
    const float* b1  = (const float*)d_in[2];
    const float* w2  = (const float*)d_in[3];
    const float* b2  = (const float*)d_in[4];
    const float* g1w = (const float*)d_in[5];
    const float* g1b = (const float*)d_in[6];
    const float* g2w = (const float*)d_in[7];
    const float* g2b = (const float*)d_in[8];
    const float* fw  = (const float*)d_in[9];
    const float* fb  = (const float*)d_in[10];

    char* ws = (char*)d_ws;
    const size_t MB = 1024 * 1024;
    unsigned short* y1t = (unsigned short*)(ws);                    // [B][1024][16] bf16, 32MB
    unsigned short* y2t = (unsigned short*)(ws + 32 * MB);          // [N][32] bf16, 32MB
    float* partials     = (float*)(ws + 64 * MB);                   // [B][4][128] fp32, 2MB
    unsigned short* Wb1 = (unsigned short*)(ws + 66 * MB);          // 4096 elems
    unsigned short* Wb2 = (unsigned short*)(ws + 66 * MB + 64 * 1024);   // 16384 elems
    unsigned short* Wc1 = (unsigned short*)(ws + 66 * MB + 128 * 1024);  // 1536 elems
    unsigned short* Wc2 = (unsigned short*)(ws + 66 * MB + 192 * 1024);  // 3072 elems
    float* out = (float*)d_out;

    repack_w<<<4, 256, 0, stream>>>(g1w, g2w, w1, w2, Wb1, Wb2, Wc1, Wc2);
    conv1_mfma<<<dim3(2, B_), 256, 0, stream>>>(x, Wc1, b1, y1t);
    conv2_mfma<<<dim3(2, B_), 256, 0, stream>>>(y1t, Wc2, b2, y2t);
    gcn_fused<<<NNODES / 128, 256, 0, stream>>>(y2t, Wb1, Wb2, g1b, g2b, partials);
    fc_kernel<<<B_, 128, 0, stream>>>(partials, fw, fb, out);
}

// Round 6
// 215.155 us; speedup vs baseline: 2.8694x; 1.0601x over previous
//
#include <hip/hip_runtime.h>
#include <hip/hip_bf16.h>

// Problem constants
#define B_      1024
#define CIN     9
#define T0_     2048
#define C1_     16
#define C2_     32
#define RT_     512
#define NNODES  (B_ * RT_)     // 524288
#define HID_    128
#define OUTF_   64

typedef __attribute__((ext_vector_type(8))) __bf16 bf16x8;
typedef __attribute__((ext_vector_type(4))) float f32x4;
typedef __attribute__((ext_vector_type(8))) unsigned short us8;

// ---------- helpers ----------
__device__ __forceinline__ float bf2f(unsigned short u) {
    union { unsigned int i; float f; } c; c.i = ((unsigned int)u) << 16; return c.f;
}
__device__ __forceinline__ unsigned short f2bf(float f) {
    union { float f; unsigned int i; } c; c.f = f;
    unsigned int i = c.i + 0x7FFFu + ((c.i >> 16) & 1u);  // round-nearest-even
    return (unsigned short)(i >> 16);
}
__device__ __forceinline__ float dinv_of(int r) {
    return (r == 0 || r == RT_ - 1) ? 0.70710678118f : 0.57735026919f;
}

// ---------- kernel R: repack all weights into bf16 MFMA fragment order ----------
// Wb1 (A-op gcn1, W1^T): e=((ft*64)+lane)*8+j = W1[k=(lane>>4)*8+j][f=ft*16+(lane&15)]
// Wb2 (B-op gcn2):       e=((ks*8+ct)*64+lane)*8+j = W2[k=ks*32+(lane>>4)*8+j][f=ct*16+(lane&15)]
// Wc1 (B-op conv1):      e=(ks*64+lane)*8+j: kk=ks*32+(lane>>4)*8+j -> ktap=kk>>4, ci=kk&15;
//                        = (ktap<5 && ci<9) ? w1[co=lane&15][ci][ktap] : 0
// Wc2 (B-op conv2):      e=((ks*2+nt)*64+lane)*8+j: co=nt*16+(lane&15); (ktap<5)?w2[co][ci][ktap]:0
// Blocks 0..4 iterate SOURCE-linear (coalesced reads, scatter writes).
__global__ __launch_bounds__(256) void repack_w(
    const float* __restrict__ W1g, const float* __restrict__ W2g,
    const float* __restrict__ Wc1g, const float* __restrict__ Wc2g,
    unsigned short* __restrict__ Wb1, unsigned short* __restrict__ Wb2,
    unsigned short* __restrict__ Wc1, unsigned short* __restrict__ Wc2)
{
    const int tid = threadIdx.x;
    const int bid = blockIdx.x;
    if (bid == 0) {
        for (int s = tid; s < 32 * 128; s += 256) {        // W1 source-linear
            int k = s >> 7, f = s & 127;
            int lane = ((k >> 3) << 4) + (f & 15);
            int e = (((f >> 4) * 64) + lane) * 8 + (k & 7);
            Wb1[e] = f2bf(W1g[s]);
        }
    } else if (bid <= 4) {
        const int s0 = (bid - 1) * 4096;
        for (int i = tid; i < 4096; i += 256) {            // W2 source-linear
            int s = s0 + i;
            int k = s >> 7, f = s & 127;
            int ks = k >> 5, lane = (((k >> 3) & 3) << 4) + (f & 15);
            int e = ((ks * 8 + (f >> 4)) * 64 + lane) * 8 + (k & 7);
            Wb2[e] = f2bf(W2g[s]);
        }
    } else if (bid == 5) {
        for (int e = tid; e < 3 * 64 * 8; e += 256) {
            int j = e & 7, lane = (e >> 3) & 63, ks = e >> 9;
            int kk = ks * 32 + (lane >> 4) * 8 + j;
            int k = kk >> 4, ci = kk & 15, co = lane & 15;
            Wc1[e] = (k < 5 && ci < CIN) ? f2bf(Wc1g[(co * CIN + ci) * 5 + k]) : 0;
        }
    } else {
        for (int e = tid; e < 3 * 2 * 64 * 8; e += 256) {
            int j = e & 7, lane = (e >> 3) & 63, nt = (e >> 9) & 1, ks = e >> 10;
            int kk = ks * 32 + (lane >> 4) * 8 + j;
            int k = kk >> 4, ci = kk & 15, co = nt * 16 + (lane & 15);
            Wc2[e] = (k < 5) ? f2bf(Wc2g[(co * C1_ + ci) * 5 + k]) : 0;
        }
    }
}

// ---------- MEGAKERNEL: conv1+pool -> conv2+pool -> gcn1 -> gcn2 -> mean partials ----------
// One block per 128-node tile. All intermediates live in LDS; HBM = x in, partials out.
// Ranges (r0 = tile*128, within-sample):
//   y2 nodes needed: r in [r0-2, r0+129]            (132, step1 needs +-1 of the +-1 halo)
//   conv2 t1 range:  [2r0-4, 2r0+259]               (264 outputs, 17 m-tiles)
//   y1 rows needed:  t1 in [2r0-6, 2r0+261]         (268 rows; OOB-t1 rows are ZERO per reference padding)
//   conv1 t range:   [4r0-12, 4r0+523]              (536 outputs, 34 m-tiles)
//   x rows staged:   xt in [4r0-14, 4r0+537]        (552 rows incl. tile pad, OOB -> 0)
__global__ __launch_bounds__(256, 2) void mega(
    const float* __restrict__ x,             // [B][9][2048] fp32
    const unsigned short* __restrict__ Wc1,  // conv1 B-frags
    const unsigned short* __restrict__ Wc2,  // conv2 B-frags
    const unsigned short* __restrict__ Wb1,  // gcn1 A-frags (W1^T)
    const unsigned short* __restrict__ Wb2,  // gcn2 B-frags
    const float* __restrict__ c1b, const float* __restrict__ c2b,
    const float* __restrict__ g1b, const float* __restrict__ g2b,
    float* __restrict__ partials)            // [B][4][128] fp32
{
    // LDS lifetime plan (bytes):
    //   xs    [0, 26496)      552*24 shorts          phases A,B
    //   As1   [0, 11520)      144*40 shorts          phases D,E   (after xs dead)
    //   y2loc [11520, 19968)  132*32 shorts          phases C,D   (after xs dead)
    //   A2    [0, 38912)      128*152 shorts         phases F,G   (after As1/y2loc dead)
    //   y1ext [39424, 48384)  280*16 shorts          phases B,C
    //   H     [39424, 74784)  130*136 shorts         phases E,F,G? (dead after F)
    //   bls1  [74784, 75296); bls2 [75296, 75808)
    __shared__ __align__(16) unsigned char lds[75808];
    unsigned short* xs    = (unsigned short*)(lds);
    unsigned short* As1   = (unsigned short*)(lds);
    unsigned short* y2loc = (unsigned short*)(lds + 11520);
    unsigned short* A2    = (unsigned short*)(lds);
    unsigned short* y1ext = (unsigned short*)(lds + 39424);
    unsigned short* H     = (unsigned short*)(lds + 39424);
    float* bls1 = (float*)(lds + 74784);
    float* bls2 = (float*)(lds + 75296);

    const int tid = threadIdx.x;
    const int b = blockIdx.x >> 2;
    const int r0 = (blockIdx.x & 3) * 128;
    const int n0 = blockIdx.x * 128;         // == b*512 + r0
    if (tid < 128) { bls1[tid] = g1b[tid]; bls2[tid] = g2b[tid]; }

    const int lane = tid & 63, wave = tid >> 6;
    const int m = lane & 15, q = lane >> 4;

    // ---- phase A: stage x as bf16 time-major: xs[s][ci], s=0..551, xt=4r0-14+s
    {
        const float* xb = x + (size_t)b * CIN * T0_;
        const int xbase = 4 * r0 - 14;
        for (int s = tid; s < 552; s += 256) {
            const int xt = xbase + s;
            us8 o0, o1;
            if (xt >= 0 && xt < T0_) {
                #pragma unroll
                for (int ci = 0; ci < 8; ci++) o0[ci] = f2bf(xb[ci * T0_ + xt]);
                o1[0] = f2bf(xb[8 * T0_ + xt]);
                #pragma unroll
                for (int jj = 1; jj < 8; jj++) o1[jj] = 0;
            } else {
                #pragma unroll
                for (int jj = 0; jj < 8; jj++) { o0[jj] = 0; o1[jj] = 0; }
            }
            *(us8*)(xs + s * 24) = o0;
            *(us8*)(xs + s * 24 + 8) = o1;
        }
    }
    __syncthreads();

    // ---- phase B: conv1 MFMA + relu + pool -> y1ext (zero for t1 outside [0,1024))
    {
        bf16x8 wf[3];
        #pragma unroll
        for (int ks = 0; ks < 3; ks++) wf[ks] = *(const bf16x8*)(Wc1 + (ks * 64 + lane) * 8);
        const float bv = c1b[m];
        const int t1base = 2 * r0 - 6;
        for (int mt = wave; mt < 34; mt += 4) {
            f32x4 acc = {};
            #pragma unroll
            for (int ks = 0; ks < 3; ks++) {
                const int row = mt * 16 + m + ks * 2 + (q >> 1);
                const bf16x8 af = *(const bf16x8*)(xs + row * 24 + (q & 1) * 8);
                acc = __builtin_amdgcn_mfma_f32_16x16x32_bf16(af, wf[ks], acc, 0, 0, 0);
            }
            const int prow = mt * 8 + q * 2;     // y1ext row; t1 = t1base + prow
            const int t1a = t1base + prow, t1b = t1a + 1;
            const float p0 = fmaxf(fmaxf(acc[0], acc[1]) + bv, 0.f);
            const float p1 = fmaxf(fmaxf(acc[2], acc[3]) + bv, 0.f);
            if (prow < 268)
                y1ext[prow * 16 + m] = (t1a >= 0 && t1a < 1024) ? f2bf(p0) : (unsigned short)0;
            if (prow + 1 < 268)
                y1ext[(prow + 1) * 16 + m] = (t1b >= 0 && t1b < 1024) ? f2bf(p1) : (unsigned short)0;
        }
        for (int idx = tid; idx < 192; idx += 256) y1ext[268 * 16 + idx] = 0;  // pad rows 268..279
    }
    __syncthreads();

    // ---- phase C: conv2 MFMA + relu + pool -> y2loc (132 nodes: r0-2 .. r0+129)
    {
        bf16x8 wf[3][2];
        #pragma unroll
        for (int ks = 0; ks < 3; ks++)
            #pragma unroll
            for (int nt = 0; nt < 2; nt++)
                wf[ks][nt] = *(const bf16x8*)(Wc2 + ((ks * 2 + nt) * 64 + lane) * 8);
        const float bv0 = c2b[m], bv1 = c2b[16 + m];
        for (int mt = wave; mt < 17; mt += 4) {
            f32x4 a0 = {}, a1 = {};
            #pragma unroll
            for (int ks = 0; ks < 3; ks++) {
                const int row = mt * 16 + m + ks * 2 + (q >> 1);
                const bf16x8 af = *(const bf16x8*)(y1ext + row * 16 + (q & 1) * 8);
                a0 = __builtin_amdgcn_mfma_f32_16x16x32_bf16(af, wf[ks][0], a0, 0, 0, 0);
                a1 = __builtin_amdgcn_mfma_f32_16x16x32_bf16(af, wf[ks][1], a1, 0, 0, 0);
            }
            const int nrow = mt * 8 + q * 2;     // y2loc row (node r0-2+nrow)
            if (nrow < 132) {
                y2loc[nrow * 32 + m]      = f2bf(fmaxf(fmaxf(a0[0], a0[1]) + bv0, 0.f));
                y2loc[nrow * 32 + 16 + m] = f2bf(fmaxf(fmaxf(a1[0], a1[1]) + bv1, 0.f));
            }
            if (nrow + 1 < 132) {
                y2loc[(nrow + 1) * 32 + m]      = f2bf(fmaxf(fmaxf(a0[2], a0[3]) + bv0, 0.f));
                y2loc[(nrow + 1) * 32 + 16 + m] = f2bf(fmaxf(fmaxf(a1[2], a1[3]) + bv1, 0.f));
            }
        }
    }
    __syncthreads();

    // ---- phase D (gcn step1): As1 row i <-> node n0-1+i (i<130), stencil from y2loc
    for (int s = tid; s < 288; s += 256) {
        const int i = s >> 1, fh = (s & 1) * 16;
        unsigned short* dst = As1 + i * 40 + fh;
        const int r = r0 - 1 + i;
        if (i >= 130 || r < 0 || r >= RT_) {
            us8 z;
            #pragma unroll
            for (int j = 0; j < 8; j++) z[j] = 0;
            *(us8*)dst = z; *(us8*)(dst + 8) = z;
        } else {
            const float dm = dinv_of(r), cm = dm * dm;
            const unsigned short* Yc = y2loc + (i + 1) * 32 + fh;   // center node
            us8 c0 = *(const us8*)(Yc), c1 = *(const us8*)(Yc + 8);
            float v[16];
            #pragma unroll
            for (int j = 0; j < 8; j++) { v[j] = cm * bf2f(c0[j]); v[8 + j] = cm * bf2f(c1[j]); }
            if (r > 0) {
                const float cl = dm * dinv_of(r - 1);
                us8 a0 = *(const us8*)(Yc - 32), a1 = *(const us8*)(Yc - 24);
                #pragma unroll
                for (int j = 0; j < 8; j++) { v[j] += cl * bf2f(a0[j]); v[8 + j] += cl * bf2f(a1[j]); }
            }
            if (r < RT_ - 1) {
                const float cr = dm * dinv_of(r + 1);
                us8 a0 = *(const us8*)(Yc + 32), a1 = *(const us8*)(Yc + 40);
                #pragma unroll
                for (int j = 0; j < 8; j++) { v[j] += cr * bf2f(a0[j]); v[8 + j] += cr * bf2f(a1[j]); }
            }
            us8 o0, o1;
            #pragma unroll
            for (int j = 0; j < 8; j++) { o0[j] = f2bf(v[j]); o1[j] = f2bf(v[8 + j]); }
            *(us8*)dst = o0; *(us8*)(dst + 8) = o1;
        }
    }
    __syncthreads();

    // ---- phase E (gcn1 MFMA): H = relu(As1 @ W1 + b1), rows 0..129
    {
        const int ft0 = wave * 2;
        const bf16x8 wf0 = *(const bf16x8*)(Wb1 + (ft0 * 64 + lane) * 8);
        const bf16x8 wf1 = *(const bf16x8*)(Wb1 + ((ft0 + 1) * 64 + lane) * 8);
        const float4 bv0 = *(const float4*)&bls1[ft0 * 16 + q * 4];
        const float4 bv1 = *(const float4*)&bls1[(ft0 + 1) * 16 + q * 4];
        #pragma unroll
        for (int nt = 0; nt < 9; nt++) {
            const bf16x8 bfr = *(const bf16x8*)(As1 + (nt * 16 + m) * 40 + q * 8);
            f32x4 a0 = {}, a1 = {};
            a0 = __builtin_amdgcn_mfma_f32_16x16x32_bf16(wf0, bfr, a0, 0, 0, 0);
            a1 = __builtin_amdgcn_mfma_f32_16x16x32_bf16(wf1, bfr, a1, 0, 0, 0);
            const int row = nt * 16 + m;
            if (row < 130) {
                ushort4 o0, o1;
                o0.x = f2bf(fmaxf(a0[0] + bv0.x, 0.f));
                o0.y = f2bf(fmaxf(a0[1] + bv0.y, 0.f));
                o0.z = f2bf(fmaxf(a0[2] + bv0.z, 0.f));
                o0.w = f2bf(fmaxf(a0[3] + bv0.w, 0.f));
                o1.x = f2bf(fmaxf(a1[0] + bv1.x, 0.f));
                o1.y = f2bf(fmaxf(a1[1] + bv1.y, 0.f));
                o1.z = f2bf(fmaxf(a1[2] + bv1.z, 0.f));
                o1.w = f2bf(fmaxf(a1[3] + bv1.w, 0.f));
                *(ushort4*)(H + row * 136 + ft0 * 16 + q * 4) = o0;
                *(ushort4*)(H + row * 136 + (ft0 + 1) * 16 + q * 4) = o1;
            }
        }
    }
    __syncthreads();

    // ---- phase F (gcn step3): A2[j] = cm*H[j+1] + cl*H[j] + cr*H[j+2], j=0..127
    {
        const int j = tid >> 1, fh = (tid & 1) * 64;
        const int r = r0 + j;
        const float dm = dinv_of(r), cm = dm * dm;
        const float cl = (r > 0) ? dm * dinv_of(r - 1) : 0.f;
        const float cr = (r < RT_ - 1) ? dm * dinv_of(r + 1) : 0.f;
        const unsigned short* Hl = H + j * 136 + fh;
        const unsigned short* Hc = Hl + 136;
        const unsigned short* Hr = Hc + 136;
        unsigned short* dst = A2 + j * 152 + fh;
        #pragma unroll
        for (int c = 0; c < 8; c++) {
            us8 cc = *(const us8*)(Hc + c * 8);
            us8 ll = *(const us8*)(Hl + c * 8);
            us8 rr = *(const us8*)(Hr + c * 8);
            us8 o;
            #pragma unroll
            for (int e = 0; e < 8; e++)
                o[e] = f2bf(cm * bf2f(cc[e]) + cl * bf2f(ll[e]) + cr * bf2f(rr[e]));
            *(us8*)(dst + c * 8) = o;
        }
    }
    __syncthreads();

    // ---- phase G (gcn2 MFMA + fused mean partials)
    bf16x8 bw[4][2];
    #pragma unroll
    for (int ks = 0; ks < 4; ks++)
        #pragma unroll
        for (int i = 0; i < 2; i++) {
            int ct = wave * 2 + i;
            bw[ks][i] = *(const bf16x8*)(Wb2 + ((size_t)((ks * 8 + ct) * 64 + lane)) * 8);
        }
    f32x4 acc[8][2] = {};
    #pragma unroll
    for (int ks = 0; ks < 4; ks++) {
        #pragma unroll
        for (int nt = 0; nt < 8; nt++) {
            const bf16x8 af = *(const bf16x8*)(A2 + (nt * 16 + m) * 152 + ks * 32 + q * 8);
            acc[nt][0] = __builtin_amdgcn_mfma_f32_16x16x32_bf16(af, bw[ks][0], acc[nt][0], 0, 0, 0);
            acc[nt][1] = __builtin_amdgcn_mfma_f32_16x16x32_bf16(af, bw[ks][1], acc[nt][1], 0, 0, 0);
        }
    }
    const float bb0 = bls2[wave * 32 + m];
    const float bb1 = bls2[wave * 32 + 16 + m];
    float s0 = 0.f, s1 = 0.f;
    #pragma unroll
    for (int nt = 0; nt < 8; nt++)
        #pragma unroll
        for (int rgi = 0; rgi < 4; rgi++) {
            s0 += fmaxf(acc[nt][0][rgi] + bb0, 0.f);
            s1 += fmaxf(acc[nt][1][rgi] + bb1, 0.f);
        }
    s0 += __shfl_xor(s0, 16, 64); s0 += __shfl_xor(s0, 32, 64);
    s1 += __shfl_xor(s1, 16, 64); s1 += __shfl_xor(s1, 32, 64);
    if (lane < 16) {
        float* p = partials + (size_t)blockIdx.x * 128 + wave * 32;
        p[m] = s0;
        p[16 + m] = s1;
    }
}

// ---------- kernel 5: mean over RT + FC ----------
__global__ __launch_bounds__(128) void fc_kernel(
    const float* __restrict__ partials, const float* __restrict__ fw,
    const float* __restrict__ fb, float* __restrict__ out)
{
    __shared__ float sm[128];
    const int b = blockIdx.x, tid = threadIdx.x;
    float s = 0.f;
    #pragma unroll
    for (int t = 0; t < 4; t++) s += partials[((b << 2) + t) * 128 + tid];
    sm[tid] = s * (1.0f / 512.0f);
    __syncthreads();
    if (tid < 64) {
        float acc = fb[tid];
        #pragma unroll 8
        for (int f = 0; f < 128; f++) acc += sm[f] * fw[f * 64 + tid];
        out[b * 64 + tid] = acc;
    }
}

extern "C" void kernel_launch(void* const* d_in, const int* in_sizes, int n_in,
                              void* d_out, int out_size, void* d_ws, size_t ws_size,
                              hipStream_t stream)
{
    const float* x   = (const float*)d_in[0];
    const float* w1  = (const float*)d_in[1];
    const float* b1  = (const float*)d_in[2];
    const float* w2  = (const float*)d_in[3];
    const float* b2  = (const float*)d_in[4];
    const float* g1w = (const float*)d_in[5];
    const float* g1b = (const float*)d_in[6];
    const float* g2w = (const float*)d_in[7];
    const float* g2b = (const float*)d_in[8];
    const float* fw  = (const float*)d_in[9];
    const float* fb  = (const float*)d_in[10];

    char* ws = (char*)d_ws;
    const size_t MB = 1024 * 1024;
    float* partials     = (float*)(ws);                              // [B][4][128] fp32, 2MB
    unsigned short* Wb1 = (unsigned short*)(ws + 2 * MB);            // 4096 elems
    unsigned short* Wb2 = (unsigned short*)(ws + 2 * MB + 16 * 1024);// 16384 elems
    unsigned short* Wc1 = (unsigned short*)(ws + 2 * MB + 64 * 1024);// 1536 elems
    unsigned short* Wc2 = (unsigned short*)(ws + 2 * MB + 80 * 1024);// 3072 elems
    float* out = (float*)d_out;

    repack_w<<<7, 256, 0, stream>>>(g1w, g2w, w1, w2, Wb1, Wb2, Wc1, Wc2);
    mega<<<NNODES / 128, 256, 0, stream>>>(x, Wc1, Wc2, Wb1, Wb2,
                                           b1, b2, g1b, g2b, partials);
    fc_kernel<<<B_, 128, 0, stream>>>(partials, fw, fb, out);
}